// Round 13
// baseline (683.563 us; speedup 1.0000x reference)
//
#include <hip/hip_runtime.h>
#include <math.h>

// FieldlineGraphForecaster round 12: node tile TE 64->32 (occupancy doubling;
// r11 showed tile kernels at ~3-6 blocks/CU are latency-bound, not VALU-bound).
// Bit-identical numerics. encab/gather/prep/sort unchanged from r11.

constexpr int H = 128;
constexpr int NTHR = 256;
constexpr int TEN = 32;   // rows per node MFMA tile (was 64)
constexpr int TILE = 32;  // rows per enc/ab/dec tile
constexpr int CHUNK = 16; // sorted edges per chunk

using bf16x8 = __attribute__((ext_vector_type(8))) short;
using f32x4  = __attribute__((ext_vector_type(4))) float;

// Branchless GELU: A&S 7.1.26 erf (5-term), |eps|<=1.5e-7. DO NOT downgrade:
// 3-term (2.5e-5) fails the harness threshold (r6: absmax 80 > 78).
__device__ __forceinline__ float gelu_fast(float x) {
    const float u = fabsf(x) * 0.70710678118654752440f;
    const float t = __builtin_amdgcn_rcpf(fmaf(0.3275911f, u, 1.f));
    float p = fmaf(1.061405429f, t, -1.453152027f);
    p = fmaf(p, t, 1.421413741f);
    p = fmaf(p, t, -0.284496736f);
    p = fmaf(p, t, 0.254829592f);
    p = p * t;
    const float e = __expf(-u * u);
    float er = fmaf(-p, e, 1.f);  // erf(|x|/sqrt2)
    er = copysignf(er, x);
    return 0.5f * x * (1.f + er);
}

__device__ __forceinline__ unsigned short f2bf(float f) {
    unsigned int u = __builtin_bit_cast(unsigned int, f);
    u = (u + 0x7fffu + ((u >> 16) & 1u)) >> 16;
    return (unsigned short)u;
}

__device__ __forceinline__ float bf2f_lo(unsigned int v) {
    return __builtin_bit_cast(float, v << 16);
}
__device__ __forceinline__ float bf2f_hi(unsigned int v) {
    return __builtin_bit_cast(float, v & 0xffff0000u);
}

// ---- merged prep: eW1t, nW2t, nW1tc(top), wcomb(bottom+cvec), deg=0 ------
__global__ __launch_bounds__(NTHR) void prep_kernel(
    const float* __restrict__ eW1, const float* __restrict__ nW2,
    const float* __restrict__ nW1, const float* __restrict__ eW2,
    const float* __restrict__ eb2, unsigned short* __restrict__ eW1t,
    unsigned short* __restrict__ nW2t, unsigned short* __restrict__ nW1tc,
    float* __restrict__ cvec, int* __restrict__ deg, int t1, int t2, int N) {
    const int i = blockIdx.x * NTHR + threadIdx.x;
    if (i < N) deg[i] = 0;
    if (i < t1) {
        const int per = 2 * H * H;
        const int l = i / per;
        const int r = i - l * per;
        const int n = r % H;
        const int k = r / H;
        eW1t[(size_t)l * per + n * 2 * H + k] = f2bf(eW1[i]);
    } else if (i < t1 + t2) {
        const int j = i - t1;
        const int per = H * H;
        const int l = j / per;
        const int r = j - l * per;
        const int n = r % H;
        const int k = r / H;
        nW2t[(size_t)l * per + n * H + k] = f2bf(nW2[j]);
    } else if (i < t1 + 2 * t2) {
        const int j = i - t1 - t2;
        const int per = H * H;
        const int l = j / per;
        const int r = j - l * per;
        const int k = r / H;
        const int o = r % H;
        nW1tc[(size_t)l * H * 2 * H + o * 2 * H + k] =
            f2bf(nW1[(size_t)l * 2 * H * H + k * H + o]);
    } else {
        const int j = i - t1 - 2 * t2;
        const int per = (H + 1) * H;
        const int l = j / per;
        const int r = j - l * per;
        if (l >= t2 / (H * H)) return;  // l < L
        const int jj = r / H;  // 0..128
        const int o = r % H;
        const float* w1 = nW1 + (size_t)l * 2 * H * H + (size_t)H * H;
        const float* row = (jj < H) ? (eW2 + (size_t)l * H * H + (size_t)jj * H)
                                    : (eb2 + (size_t)l * H);
        float s = 0.f;
#pragma unroll 4
        for (int c = 0; c < H; ++c) s = fmaf(row[c], w1[(size_t)c * H + o], s);
        if (jj < H)
            nW1tc[(size_t)l * H * 2 * H + o * 2 * H + H + jj] = f2bf(s);
        else
            cvec[(size_t)l * H + o] = s;
    }
}

// ----------------------- sort-by-dst machinery ----------------------------
__global__ __launch_bounds__(NTHR) void deg_kernel(const int* __restrict__ dst,
                                                   int* __restrict__ deg, int E) {
    const int e = blockIdx.x * NTHR + threadIdx.x;
    if (e < E) atomicAdd(&deg[dst[e]], 1);
}

__global__ __launch_bounds__(1024) void scan1_kernel(
    const int* __restrict__ deg, int* __restrict__ out,
    int* __restrict__ bsum, int N) {
    __shared__ int buf[1024];
    const int t = threadIdx.x;
    const int i = blockIdx.x * 1024 + t;
    const int x = (i < N) ? deg[i] : 0;
    buf[t] = x;
    __syncthreads();
    int v = x;
    for (int off = 1; off < 1024; off <<= 1) {
        const int y = (t >= off) ? buf[t - off] : 0;
        __syncthreads();
        v += y;
        buf[t] = v;
        __syncthreads();
    }
    if (i < N) out[i] = v - x;  // block-local exclusive
    if (t == 1023) bsum[blockIdx.x] = v;
}

__global__ void scan2_kernel(int* __restrict__ bsum, int nb) {
    if (threadIdx.x == 0) {
        int acc = 0;
        for (int i = 0; i < nb; ++i) {
            const int t = bsum[i];
            bsum[i] = acc;
            acc += t;
        }
    }
}

__global__ __launch_bounds__(NTHR) void scan3_kernel(
    int* __restrict__ out, int* __restrict__ cursor,
    const int* __restrict__ bsum, int* __restrict__ chunkLo, int N, int E,
    int numChunks) {
    const int i = blockIdx.x * NTHR + threadIdx.x;
    if (i < N) {
        const int v = out[i] + bsum[i >> 10];
        out[i] = v;
        cursor[i] = v;
    } else if (i == N) {
        out[N] = E;
    }
    if (i < numChunks) chunkLo[i] = 0x7fffffff;
}

// merged: chunkLo atomicMin + dst-sorted scatter
// srcS holds BYTE offsets into A (src * H * 2)
__global__ __launch_bounds__(NTHR) void finalize_kernel(
    const int* __restrict__ rowStart, int* __restrict__ chunkLo,
    const int* __restrict__ src, const int* __restrict__ dst,
    int* __restrict__ cursor, int* __restrict__ srcS, int N, int E) {
    const int i = blockIdx.x * NTHR + threadIdx.x;
    if (i < N) atomicMin(&chunkLo[rowStart[i] / CHUNK], i);
    if (i < E) {
        const int pos = atomicAdd(&cursor[dst[i]], 1);
        srcS[pos] = src[i] << 8;  // * 256 bytes per A row
    }
}

// ---------------- fp32 helper for encoder/decoder -------------------------
template <int K4>
__device__ __forceinline__ void mlp_layer(const float* __restrict__ W,
                                          const float* lds, int ldsStride,
                                          int c0, int egBase,
                                          float a0[8], float a1[8]) {
#pragma unroll 2
    for (int k4 = 0; k4 < K4; ++k4) {
        const float w00 = W[(k4 * 4 + 0) * H + c0];
        const float w01 = W[(k4 * 4 + 1) * H + c0];
        const float w02 = W[(k4 * 4 + 2) * H + c0];
        const float w03 = W[(k4 * 4 + 3) * H + c0];
        const float w10 = W[(k4 * 4 + 0) * H + c0 + 64];
        const float w11 = W[(k4 * 4 + 1) * H + c0 + 64];
        const float w12 = W[(k4 * 4 + 2) * H + c0 + 64];
        const float w13 = W[(k4 * 4 + 3) * H + c0 + 64];
#pragma unroll
        for (int e = 0; e < 8; ++e) {
            const float4 x = *reinterpret_cast<const float4*>(
                &lds[(egBase + e) * ldsStride + k4 * 4]);
            a0[e] = fmaf(x.x, w00, a0[e]);
            a0[e] = fmaf(x.y, w01, a0[e]);
            a0[e] = fmaf(x.z, w02, a0[e]);
            a0[e] = fmaf(x.w, w03, a0[e]);
            a1[e] = fmaf(x.x, w10, a1[e]);
            a1[e] = fmaf(x.y, w11, a1[e]);
            a1[e] = fmaf(x.z, w12, a1[e]);
            a1[e] = fmaf(x.w, w13, a1[e]);
        }
    }
}

// ---- FUSED encode+ab (32-row tile): nf -> h,h_bf; h_bf (LDS) -> A,B ------
__global__ __launch_bounds__(NTHR) void encab_kernel(
    const float* __restrict__ nf, const float* __restrict__ W1,
    const float* __restrict__ b1, const float* __restrict__ W2,
    const float* __restrict__ b2, float* __restrict__ h,
    unsigned short* __restrict__ h_bf,
    const unsigned short* __restrict__ eW1t,  // layer 0, [128 col][256 k]
    const float* __restrict__ eb1, unsigned short* __restrict__ A,
    float* __restrict__ Bout, int N) {
    __shared__ float xin[TILE * 16];                          // 2KB
    __shared__ float hm[TILE * H];                            // 16KB
    __shared__ __align__(16) unsigned short X[TILE * H];      // 8KB swizzled
    const int t = threadIdx.x;
    const int lane = t & 63;
    const int w = t >> 6;
    const int n0 = blockIdx.x * TILE;
    const int c0 = t & 63;
    const int eg = t >> 6;
    const int l15 = lane & 15;
    const int lq = lane >> 4;

    // ---- encode ----
    for (int i = t; i < TILE * 16; i += NTHR) {
        const int gi = n0 * 16 + i;
        xin[i] = (gi < N * 16) ? nf[gi] : 0.f;
    }
    __syncthreads();

    float a0[8], a1[8];
#pragma unroll
    for (int e = 0; e < 8; ++e) { a0[e] = 0.f; a1[e] = 0.f; }
    mlp_layer<4>(W1, xin, 16, c0, eg * 8, a0, a1);
    {
        const float bb0 = b1[c0], bb1 = b1[c0 + 64];
#pragma unroll
        for (int e = 0; e < 8; ++e) {
            hm[(eg * 8 + e) * H + c0] = gelu_fast(a0[e] + bb0);
            hm[(eg * 8 + e) * H + c0 + 64] = gelu_fast(a1[e] + bb1);
        }
    }
    __syncthreads();
#pragma unroll
    for (int e = 0; e < 8; ++e) { a0[e] = 0.f; a1[e] = 0.f; }
    mlp_layer<32>(W2, hm, H, c0, eg * 8, a0, a1);
    {
        const float bb0 = b2[c0], bb1 = b2[c0 + 64];
#pragma unroll
        for (int e = 0; e < 8; ++e) {
            const int row = eg * 8 + e;
            const int n = n0 + row;
            unsigned short hb0 = 0, hb1 = 0;
            if (n < N) {
                const float v0 = a0[e] + bb0, v1 = a1[e] + bb1;
                h[(size_t)n * H + c0] = v0;
                h[(size_t)n * H + c0 + 64] = v1;
                hb0 = f2bf(v0);
                hb1 = f2bf(v1);
                h_bf[(size_t)n * H + c0] = hb0;
                h_bf[(size_t)n * H + c0 + 64] = hb1;
            }
            const int bo0 = row * 256 + ((c0 * 2) ^ ((row & 7) << 4));
            const int bo1 = row * 256 + (((c0 + 64) * 2) ^ ((row & 7) << 4));
            *reinterpret_cast<unsigned short*>(reinterpret_cast<char*>(X) + bo0) = hb0;
            *reinterpret_cast<unsigned short*>(reinterpret_cast<char*>(X) + bo1) = hb1;
        }
    }

    // ---- ab (32 rows) ----
    const int half = w >> 1;  // 0 -> A (k 0..127), 1 -> B (k 128..255)
    const int cbase = (w & 1) * 64;
    bf16x8 Bf[4][4];
#pragma unroll
    for (int cg = 0; cg < 4; ++cg) {
        const int col = cbase + cg * 16 + l15;
#pragma unroll
        for (int s = 0; s < 4; ++s)
            Bf[cg][s] = *reinterpret_cast<const bf16x8*>(
                eW1t + (size_t)col * 256 + half * 128 + s * 32 + lq * 8);
    }
    __syncthreads();

    f32x4 acc[2][4];
#pragma unroll
    for (int rg = 0; rg < 2; ++rg)
#pragma unroll
        for (int cg = 0; cg < 4; ++cg) acc[rg][cg] = (f32x4)0.f;

#pragma unroll
    for (int s = 0; s < 4; ++s) {
        bf16x8 a[2];
#pragma unroll
        for (int rg = 0; rg < 2; ++rg) {
            const int row = rg * 16 + l15;
            const int byteoff = row * 256 + ((s * 64 + lq * 16) ^ ((row & 7) << 4));
            a[rg] = *reinterpret_cast<const bf16x8*>(
                reinterpret_cast<const char*>(X) + byteoff);
        }
#pragma unroll
        for (int rg = 0; rg < 2; ++rg)
#pragma unroll
            for (int cg = 0; cg < 4; ++cg)
                acc[rg][cg] = __builtin_amdgcn_mfma_f32_16x16x32_bf16(
                    a[rg], Bf[cg][s], acc[rg][cg], 0, 0, 0);
    }

#pragma unroll
    for (int cg = 0; cg < 4; ++cg) {
        const int col = cbase + cg * 16 + l15;
        const float bb = (half == 1) ? eb1[col] : 0.f;
#pragma unroll
        for (int rg = 0; rg < 2; ++rg) {
#pragma unroll
            for (int r = 0; r < 4; ++r) {
                const int row = rg * 16 + lq * 4 + r;
                const int n = n0 + row;
                if (n < N) {
                    if (half == 0)
                        A[(size_t)n * H + col] = f2bf(acc[rg][cg][r]);
                    else
                        Bout[(size_t)n * H + col] = acc[rg][cg][r] + bb;
                }
            }
        }
    }
}

// ---- edge gather: one wave per chunk, 2 cols/lane, 8-edge ILP window -----
__global__ __launch_bounds__(NTHR) void edge_gather_kernel(
    const unsigned short* __restrict__ A, const float* __restrict__ B,
    const int* __restrict__ srcS, const int* __restrict__ rowStart,  // N+1
    const int* __restrict__ chunkLo, unsigned short* __restrict__ aggB,
    int N, int E) {
    const int lane = threadIdx.x & 63;
    const int c = blockIdx.x * 4 + (threadIdx.x >> 6);
    const int nWaves = E / CHUNK + 1;
    if (c >= nWaves) return;
    int n = chunkLo[c];
    if (n >= N) return;  // sentinel: no node starts in this chunk
    const int Wend = (c + 1) * CHUNK;
    const int c2 = lane * 2;
    const char* Abase = (const char*)A + (size_t)(lane * 4);
    int r0 = rowStart[n];
    while (true) {
        const int r1 = rowStart[n + 1];
        const float2 bv = *reinterpret_cast<const float2*>(B + (size_t)n * H + c2);
        float s0 = 0.f, s1 = 0.f;
        int e = r0;
        for (; e + 8 <= r1; e += 8) {
            const int sa = srcS[e];
            const int sb = srcS[e + 1];
            const int sc = srcS[e + 2];
            const int sd = srcS[e + 3];
            const int se = srcS[e + 4];
            const int sf = srcS[e + 5];
            const int sg = srcS[e + 6];
            const int sh = srcS[e + 7];
            const unsigned int va = *reinterpret_cast<const unsigned int*>(Abase + sa);
            const unsigned int vb = *reinterpret_cast<const unsigned int*>(Abase + sb);
            const unsigned int vc = *reinterpret_cast<const unsigned int*>(Abase + sc);
            const unsigned int vd = *reinterpret_cast<const unsigned int*>(Abase + sd);
            const unsigned int ve = *reinterpret_cast<const unsigned int*>(Abase + se);
            const unsigned int vf = *reinterpret_cast<const unsigned int*>(Abase + sf);
            const unsigned int vg = *reinterpret_cast<const unsigned int*>(Abase + sg);
            const unsigned int vh = *reinterpret_cast<const unsigned int*>(Abase + sh);
            s0 += gelu_fast(bf2f_lo(va) + bv.x);
            s1 += gelu_fast(bf2f_hi(va) + bv.y);
            s0 += gelu_fast(bf2f_lo(vb) + bv.x);
            s1 += gelu_fast(bf2f_hi(vb) + bv.y);
            s0 += gelu_fast(bf2f_lo(vc) + bv.x);
            s1 += gelu_fast(bf2f_hi(vc) + bv.y);
            s0 += gelu_fast(bf2f_lo(vd) + bv.x);
            s1 += gelu_fast(bf2f_hi(vd) + bv.y);
            s0 += gelu_fast(bf2f_lo(ve) + bv.x);
            s1 += gelu_fast(bf2f_hi(ve) + bv.y);
            s0 += gelu_fast(bf2f_lo(vf) + bv.x);
            s1 += gelu_fast(bf2f_hi(vf) + bv.y);
            s0 += gelu_fast(bf2f_lo(vg) + bv.x);
            s1 += gelu_fast(bf2f_hi(vg) + bv.y);
            s0 += gelu_fast(bf2f_lo(vh) + bv.x);
            s1 += gelu_fast(bf2f_hi(vh) + bv.y);
        }
        for (; e + 4 <= r1; e += 4) {
            const int sa = srcS[e];
            const int sb = srcS[e + 1];
            const int sc = srcS[e + 2];
            const int sd = srcS[e + 3];
            const unsigned int va = *reinterpret_cast<const unsigned int*>(Abase + sa);
            const unsigned int vb = *reinterpret_cast<const unsigned int*>(Abase + sb);
            const unsigned int vc = *reinterpret_cast<const unsigned int*>(Abase + sc);
            const unsigned int vd = *reinterpret_cast<const unsigned int*>(Abase + sd);
            s0 += gelu_fast(bf2f_lo(va) + bv.x);
            s1 += gelu_fast(bf2f_hi(va) + bv.y);
            s0 += gelu_fast(bf2f_lo(vb) + bv.x);
            s1 += gelu_fast(bf2f_hi(vb) + bv.y);
            s0 += gelu_fast(bf2f_lo(vc) + bv.x);
            s1 += gelu_fast(bf2f_hi(vc) + bv.y);
            s0 += gelu_fast(bf2f_lo(vd) + bv.x);
            s1 += gelu_fast(bf2f_hi(vd) + bv.y);
        }
        for (; e < r1; ++e) {
            const unsigned int av =
                *reinterpret_cast<const unsigned int*>(Abase + srcS[e]);
            s0 += gelu_fast(bf2f_lo(av) + bv.x);
            s1 += gelu_fast(bf2f_hi(av) + bv.y);
        }
        const unsigned int packed =
            (unsigned int)f2bf(s0) | ((unsigned int)f2bf(s1) << 16);
        *reinterpret_cast<unsigned int*>(aggB + (size_t)n * H + c2) = packed;
        if (++n >= N) break;
        r0 = r1;
        if (r0 >= Wend) break;
    }
}

// ---- fused node update, TEN=32 rows (+ next-layer A/B production) --------
// h += MLP([h | aggB]; W1'=[nW1_top;Wcomb], b1'=b1+deg*cvec); refresh h_bf.
// If PROD: A_out = h_new@eW1_top(next), B_out = h_new@eW1_bot(next)+eb1(next).
template <bool PROD>
__global__ __launch_bounds__(NTHR) void node_fused_kernel(
    float* __restrict__ h, unsigned short* __restrict__ h_bf,
    const unsigned short* __restrict__ aggB, const int* __restrict__ deg,
    const unsigned short* __restrict__ W1tc, const float* __restrict__ b1,
    const float* __restrict__ cvec, const unsigned short* __restrict__ W2t,
    const float* __restrict__ b2, const unsigned short* __restrict__ eW1tN,
    const float* __restrict__ eb1N, unsigned short* __restrict__ A_out,
    float* __restrict__ B_out, int N) {
    __shared__ __align__(16) unsigned short X[TEN * 256];  // 16KB
    __shared__ int degS[TEN];
    const int t = threadIdx.x;
    const int lane = t & 63;
    const int w = t >> 6;
    const int n0 = blockIdx.x * TEN;
    const int l15 = lane & 15;
    const int lq = lane >> 4;

    if (t < TEN) degS[t] = (n0 + t < N) ? deg[n0 + t] : 0;
#pragma unroll
    for (int i = 0; i < 4; ++i) {
        const int c = i * NTHR + t;
        const int row = c >> 5;
        const int col8 = c & 31;
        const int n = n0 + row;
        int4 v = make_int4(0, 0, 0, 0);
        if (n < N) {
            const unsigned short* srcp = (col8 < 16) ? h_bf : aggB;
            v = *reinterpret_cast<const int4*>(srcp + (size_t)n * H +
                                               (col8 & 15) * 8);
        }
        const int byteoff = row * 512 + ((col8 * 16) ^ ((row & 7) << 4));
        *reinterpret_cast<int4*>(reinterpret_cast<char*>(X) + byteoff) = v;
    }

    bf16x8 B1[2][8];
#pragma unroll
    for (int cg = 0; cg < 2; ++cg) {
        const int col = w * 32 + cg * 16 + l15;
#pragma unroll
        for (int s = 0; s < 8; ++s)
            B1[cg][s] = *reinterpret_cast<const bf16x8*>(
                W1tc + (size_t)col * 256 + s * 32 + lq * 8);
    }
    __syncthreads();

    f32x4 acc[2][2];
#pragma unroll
    for (int rg = 0; rg < 2; ++rg)
#pragma unroll
        for (int cg = 0; cg < 2; ++cg) acc[rg][cg] = (f32x4)0.f;

#pragma unroll
    for (int s = 0; s < 8; ++s) {
        bf16x8 a[2];
#pragma unroll
        for (int rg = 0; rg < 2; ++rg) {
            const int row = rg * 16 + l15;
            const int byteoff = row * 512 + ((s * 64 + lq * 16) ^ ((row & 7) << 4));
            a[rg] = *reinterpret_cast<const bf16x8*>(
                reinterpret_cast<const char*>(X) + byteoff);
        }
#pragma unroll
        for (int rg = 0; rg < 2; ++rg)
#pragma unroll
            for (int cg = 0; cg < 2; ++cg)
                acc[rg][cg] = __builtin_amdgcn_mfma_f32_16x16x32_bf16(
                    a[rg], B1[cg][s], acc[rg][cg], 0, 0, 0);
    }
    __syncthreads();

    // L1 epilogue: gelu(acc + b1 + deg*cvec) -> hm (LDS bytes 0..8K)
#pragma unroll
    for (int cg = 0; cg < 2; ++cg) {
        const int col = w * 32 + cg * 16 + l15;
        const float bb = b1[col];
        const float cc = cvec[col];
#pragma unroll
        for (int rg = 0; rg < 2; ++rg) {
#pragma unroll
            for (int r = 0; r < 4; ++r) {
                const int row = rg * 16 + lq * 4 + r;
                const float v =
                    gelu_fast(acc[rg][cg][r] + bb + (float)degS[row] * cc);
                const int byteoff = row * 256 + ((col * 2) ^ ((row & 7) << 4));
                *reinterpret_cast<unsigned short*>(
                    reinterpret_cast<char*>(X) + byteoff) = f2bf(v);
            }
        }
    }

    bf16x8 B2[2][4];
#pragma unroll
    for (int cg = 0; cg < 2; ++cg) {
        const int col = w * 32 + cg * 16 + l15;
#pragma unroll
        for (int s = 0; s < 4; ++s)
            B2[cg][s] = *reinterpret_cast<const bf16x8*>(
                W2t + (size_t)col * 128 + s * 32 + lq * 8);
    }
    __syncthreads();

    f32x4 acc2[2][2];
#pragma unroll
    for (int rg = 0; rg < 2; ++rg)
#pragma unroll
        for (int cg = 0; cg < 2; ++cg) acc2[rg][cg] = (f32x4)0.f;

#pragma unroll
    for (int s = 0; s < 4; ++s) {
        bf16x8 a[2];
#pragma unroll
        for (int rg = 0; rg < 2; ++rg) {
            const int row = rg * 16 + l15;
            const int byteoff = row * 256 + ((s * 64 + lq * 16) ^ ((row & 7) << 4));
            a[rg] = *reinterpret_cast<const bf16x8*>(
                reinterpret_cast<const char*>(X) + byteoff);
        }
#pragma unroll
        for (int rg = 0; rg < 2; ++rg)
#pragma unroll
            for (int cg = 0; cg < 2; ++cg)
                acc2[rg][cg] = __builtin_amdgcn_mfma_f32_16x16x32_bf16(
                    a[rg], B2[cg][s], acc2[rg][cg], 0, 0, 0);
    }

    // residual write: h += update; refresh h_bf; h_new bf16 -> LDS @8KB
#pragma unroll
    for (int cg = 0; cg < 2; ++cg) {
        const int col = w * 32 + cg * 16 + l15;
        const float bb = b2[col];
#pragma unroll
        for (int rg = 0; rg < 2; ++rg) {
#pragma unroll
            for (int r = 0; r < 4; ++r) {
                const int row = rg * 16 + lq * 4 + r;
                const int n = n0 + row;
                if (n < N) {
                    const float hv = h[(size_t)n * H + col] + acc2[rg][cg][r] + bb;
                    h[(size_t)n * H + col] = hv;
                    const unsigned short hb = f2bf(hv);
                    h_bf[(size_t)n * H + col] = hb;
                    if (PROD) {
                        const int byteoff =
                            8192 + row * 256 + ((col * 2) ^ ((row & 7) << 4));
                        *reinterpret_cast<unsigned short*>(
                            reinterpret_cast<char*>(X) + byteoff) = hb;
                    }
                } else if (PROD) {
                    const int byteoff =
                        8192 + row * 256 + ((col * 2) ^ ((row & 7) << 4));
                    *reinterpret_cast<unsigned short*>(
                        reinterpret_cast<char*>(X) + byteoff) = 0;
                }
            }
        }
    }

    if (PROD) {
        bf16x8 B3[2][4], B4[2][4];
#pragma unroll
        for (int cg = 0; cg < 2; ++cg) {
            const int col = w * 32 + cg * 16 + l15;
#pragma unroll
            for (int s = 0; s < 4; ++s) {
                B3[cg][s] = *reinterpret_cast<const bf16x8*>(
                    eW1tN + (size_t)col * 256 + s * 32 + lq * 8);
                B4[cg][s] = *reinterpret_cast<const bf16x8*>(
                    eW1tN + (size_t)col * 256 + 128 + s * 32 + lq * 8);
            }
        }
        __syncthreads();

        f32x4 acc3[2][2], acc4[2][2];
#pragma unroll
        for (int rg = 0; rg < 2; ++rg)
#pragma unroll
            for (int cg = 0; cg < 2; ++cg) {
                acc3[rg][cg] = (f32x4)0.f;
                acc4[rg][cg] = (f32x4)0.f;
            }

#pragma unroll
        for (int s = 0; s < 4; ++s) {
            bf16x8 a[2];
#pragma unroll
            for (int rg = 0; rg < 2; ++rg) {
                const int row = rg * 16 + l15;
                const int byteoff =
                    8192 + row * 256 + ((s * 64 + lq * 16) ^ ((row & 7) << 4));
                a[rg] = *reinterpret_cast<const bf16x8*>(
                    reinterpret_cast<const char*>(X) + byteoff);
            }
#pragma unroll
            for (int rg = 0; rg < 2; ++rg)
#pragma unroll
                for (int cg = 0; cg < 2; ++cg) {
                    acc3[rg][cg] = __builtin_amdgcn_mfma_f32_16x16x32_bf16(
                        a[rg], B3[cg][s], acc3[rg][cg], 0, 0, 0);
                    acc4[rg][cg] = __builtin_amdgcn_mfma_f32_16x16x32_bf16(
                        a[rg], B4[cg][s], acc4[rg][cg], 0, 0, 0);
                }
        }

#pragma unroll
        for (int cg = 0; cg < 2; ++cg) {
            const int col = w * 32 + cg * 16 + l15;
            const float bb = eb1N[col];
#pragma unroll
            for (int rg = 0; rg < 2; ++rg) {
#pragma unroll
                for (int r = 0; r < 4; ++r) {
                    const int row = rg * 16 + lq * 4 + r;
                    const int n = n0 + row;
                    if (n < N) {
                        A_out[(size_t)n * H + col] = f2bf(acc3[rg][cg][r]);
                        B_out[(size_t)n * H + col] = acc4[rg][cg][r] + bb;
                    }
                }
            }
        }
    }
}

// --------------- decoder: h -> GELU MLP -> out [N,8] ----------------------
__global__ __launch_bounds__(NTHR) void decode_kernel(
    const float* __restrict__ h, const float* __restrict__ W1,
    const float* __restrict__ b1, const float* __restrict__ W2,
    const float* __restrict__ b2, float* __restrict__ out, int N) {
    __shared__ float xin[TILE * H];
    __shared__ float hm[TILE * 132];
    const int t = threadIdx.x;
    const int n0 = blockIdx.x * TILE;
    const int c0 = t & 63;
    const int eg = t >> 6;
    {
        const int col = t & 127;
        for (int e = t >> 7; e < TILE; e += 2) {
            const int n = n0 + e;
            xin[e * H + col] = (n < N) ? h[(size_t)n * H + col] : 0.f;
        }
    }
    __syncthreads();

    float a0[8], a1[8];
#pragma unroll
    for (int e = 0; e < 8; ++e) { a0[e] = 0.f; a1[e] = 0.f; }
    mlp_layer<32>(W1, xin, H, c0, eg * 8, a0, a1);
    {
        const float bb0 = b1[c0], bb1 = b1[c0 + 64];
#pragma unroll
        for (int e = 0; e < 8; ++e) {
            hm[(eg * 8 + e) * 132 + c0] = gelu_fast(a0[e] + bb0);
            hm[(eg * 8 + e) * 132 + c0 + 64] = gelu_fast(a1[e] + bb1);
        }
    }
    __syncthreads();
    {
        const int e = t >> 3;
        const int o = t & 7;
        const int n = n0 + e;
        float acc = b2[o];
#pragma unroll 4
        for (int k = 0; k < H; ++k)
            acc = fmaf(hm[e * 132 + k], W2[k * 8 + o], acc);
        if (n < N) out[n * 8 + o] = acc;
    }
}

extern "C" void kernel_launch(void* const* d_in, const int* in_sizes, int n_in,
                              void* d_out, int out_size, void* d_ws,
                              size_t ws_size, hipStream_t stream) {
    (void)n_in; (void)out_size; (void)ws_size;
    const float* nf      = (const float*)d_in[0];
    const int*   ei      = (const int*)d_in[1];
    const float* enc_W1  = (const float*)d_in[2];
    const float* enc_b1  = (const float*)d_in[3];
    const float* enc_W2  = (const float*)d_in[4];
    const float* enc_b2  = (const float*)d_in[5];
    const float* edge_W1 = (const float*)d_in[6];
    const float* edge_b1 = (const float*)d_in[7];
    const float* edge_W2 = (const float*)d_in[8];
    const float* edge_b2 = (const float*)d_in[9];
    const float* node_W1 = (const float*)d_in[10];
    const float* node_b1 = (const float*)d_in[11];
    const float* node_W2 = (const float*)d_in[12];
    const float* node_b2 = (const float*)d_in[13];
    const float* dec_W1  = (const float*)d_in[14];
    const float* dec_b1  = (const float*)d_in[15];
    const float* dec_W2  = (const float*)d_in[16];
    const float* dec_b2  = (const float*)d_in[17];

    const int N = in_sizes[0] / 16;
    const int E = in_sizes[1] / 2;
    const int L = in_sizes[7] / H;  // edge_b1 is [L,H]
    const int numChunks = E / CHUNK + 1;

    // ---------------- workspace layout ----------------
    char* ws = (char*)d_ws;
    float* h    = (float*)ws;                    ws += (size_t)N * H * 4;
    float* Bf32 = (float*)ws;                    ws += (size_t)N * H * 4;
    unsigned short* h_bf = (unsigned short*)ws;  ws += (size_t)N * H * 2;
    unsigned short* A_bf = (unsigned short*)ws;  ws += (size_t)N * H * 2;
    unsigned short* aggB = (unsigned short*)ws;  ws += (size_t)N * H * 2;
    int* srcS     = (int*)ws;                    ws += (size_t)E * 4;
    int* deg      = (int*)ws;                    ws += (size_t)N * 4;
    int* rowStart = (int*)ws;                    ws += (size_t)(N + 1) * 4;
    int* cursor   = (int*)ws;                    ws += (size_t)N * 4;
    int* bsum     = (int*)ws;                    ws += (size_t)256 * 4;
    int* chunkLo  = (int*)ws;                    ws += (size_t)numChunks * 4;
    unsigned short* eW1t = (unsigned short*)ws;  ws += (size_t)L * 2 * H * H * 2;
    unsigned short* nW1tc = (unsigned short*)ws; ws += (size_t)L * 2 * H * H * 2;
    unsigned short* nW2t = (unsigned short*)ws;  ws += (size_t)L * H * H * 2;
    float* cvec   = (float*)ws;                  ws += (size_t)L * H * 4;

    const int* srcArr = ei;
    const int* dstArr = ei + E;

    // ---- merged weight prep + wcomb + deg zeroing (one dispatch) ----
    {
        const int t1 = L * 2 * H * H, t2 = L * H * H;
        const int total = t1 + 2 * t2 + L * (H + 1) * H;
        prep_kernel<<<(total + NTHR - 1) / NTHR, NTHR, 0, stream>>>(
            edge_W1, node_W2, node_W1, edge_W2, edge_b2, eW1t, nW2t, nW1tc,
            cvec, deg, t1, t2, N);
    }

    // ---- sort edges by dst (hist + multiblock scan + merged finalize) ----
    deg_kernel<<<(E + NTHR - 1) / NTHR, NTHR, 0, stream>>>(dstArr, deg, E);
    const int nScanB = (N + 1023) / 1024;
    scan1_kernel<<<nScanB, 1024, 0, stream>>>(deg, rowStart, bsum, N);
    scan2_kernel<<<1, 64, 0, stream>>>(bsum, nScanB);
    const int scan3Span = (N + 1 > numChunks) ? (N + 1) : numChunks;
    scan3_kernel<<<(scan3Span + NTHR - 1) / NTHR, NTHR, 0, stream>>>(
        rowStart, cursor, bsum, chunkLo, N, E, numChunks);
    const int finSpan = (N > E) ? N : E;
    finalize_kernel<<<(finSpan + NTHR - 1) / NTHR, NTHR, 0, stream>>>(
        rowStart, chunkLo, srcArr, dstArr, cursor, srcS, N, E);

    const int encBlocks  = (N + TILE - 1) / TILE;
    const int nodeBlocks = (N + TEN - 1) / TEN;
    const int gatherBlks = (numChunks + 3) / 4;

    // fused encode + layer-0 A/B production
    encab_kernel<<<encBlocks, NTHR, 0, stream>>>(
        nf, enc_W1, enc_b1, enc_W2, enc_b2, h, h_bf, eW1t, edge_b1, A_bf,
        Bf32, N);
    for (int l = 0; l < L; ++l) {
        edge_gather_kernel<<<gatherBlks, NTHR, 0, stream>>>(
            A_bf, Bf32, srcS, rowStart, chunkLo, aggB, N, E);
        if (l + 1 < L) {
            node_fused_kernel<true><<<nodeBlocks, NTHR, 0, stream>>>(
                h, h_bf, aggB, deg, nW1tc + (size_t)l * 2 * H * H,
                node_b1 + (size_t)l * H, cvec + (size_t)l * H,
                nW2t + (size_t)l * H * H, node_b2 + (size_t)l * H,
                eW1t + (size_t)(l + 1) * 2 * H * H,
                edge_b1 + (size_t)(l + 1) * H, A_bf, Bf32, N);
        } else {
            node_fused_kernel<false><<<nodeBlocks, NTHR, 0, stream>>>(
                h, h_bf, aggB, deg, nW1tc + (size_t)l * 2 * H * H,
                node_b1 + (size_t)l * H, cvec + (size_t)l * H,
                nW2t + (size_t)l * H * H, node_b2 + (size_t)l * H, nullptr,
                nullptr, nullptr, nullptr, N);
        }
    }
    decode_kernel<<<encBlocks, NTHR, 0, stream>>>(h, dec_W1, dec_b1, dec_W2,
                                                  dec_b2, (float*)d_out, N);
}

// Round 14
// 677.407 us; speedup vs baseline: 1.0091x; 1.0091x over previous
//
#include <hip/hip_runtime.h>
#include <math.h>

// FieldlineGraphForecaster round 13: r11 config (best, 676us: node TE=64,
// fused encab, merged prep) + decode fused into the LAST node_fused dispatch
// (h_new passes through LDS fp32; decode math verbatim -> bit-identical).
// r12 lesson: node tile 32 regressed (not occupancy-bound); reverted.

constexpr int H = 128;
constexpr int NTHR = 256;
constexpr int TE = 64;    // rows per node MFMA tile
constexpr int TILE = 32;  // rows per enc/ab tile
constexpr int CHUNK = 16; // sorted edges per chunk

using bf16x8 = __attribute__((ext_vector_type(8))) short;
using f32x4  = __attribute__((ext_vector_type(4))) float;

// Branchless GELU: A&S 7.1.26 erf (5-term), |eps|<=1.5e-7. DO NOT downgrade:
// 3-term (2.5e-5) fails the harness threshold (r6: absmax 80 > 78).
__device__ __forceinline__ float gelu_fast(float x) {
    const float u = fabsf(x) * 0.70710678118654752440f;
    const float t = __builtin_amdgcn_rcpf(fmaf(0.3275911f, u, 1.f));
    float p = fmaf(1.061405429f, t, -1.453152027f);
    p = fmaf(p, t, 1.421413741f);
    p = fmaf(p, t, -0.284496736f);
    p = fmaf(p, t, 0.254829592f);
    p = p * t;
    const float e = __expf(-u * u);
    float er = fmaf(-p, e, 1.f);  // erf(|x|/sqrt2)
    er = copysignf(er, x);
    return 0.5f * x * (1.f + er);
}

__device__ __forceinline__ unsigned short f2bf(float f) {
    unsigned int u = __builtin_bit_cast(unsigned int, f);
    u = (u + 0x7fffu + ((u >> 16) & 1u)) >> 16;
    return (unsigned short)u;
}

__device__ __forceinline__ float bf2f_lo(unsigned int v) {
    return __builtin_bit_cast(float, v << 16);
}
__device__ __forceinline__ float bf2f_hi(unsigned int v) {
    return __builtin_bit_cast(float, v & 0xffff0000u);
}

// ---- merged prep: eW1t, nW2t, nW1tc(top), wcomb(bottom+cvec), deg=0 ------
__global__ __launch_bounds__(NTHR) void prep_kernel(
    const float* __restrict__ eW1, const float* __restrict__ nW2,
    const float* __restrict__ nW1, const float* __restrict__ eW2,
    const float* __restrict__ eb2, unsigned short* __restrict__ eW1t,
    unsigned short* __restrict__ nW2t, unsigned short* __restrict__ nW1tc,
    float* __restrict__ cvec, int* __restrict__ deg, int t1, int t2, int N) {
    const int i = blockIdx.x * NTHR + threadIdx.x;
    if (i < N) deg[i] = 0;
    if (i < t1) {
        const int per = 2 * H * H;
        const int l = i / per;
        const int r = i - l * per;
        const int n = r % H;
        const int k = r / H;
        eW1t[(size_t)l * per + n * 2 * H + k] = f2bf(eW1[i]);
    } else if (i < t1 + t2) {
        const int j = i - t1;
        const int per = H * H;
        const int l = j / per;
        const int r = j - l * per;
        const int n = r % H;
        const int k = r / H;
        nW2t[(size_t)l * per + n * H + k] = f2bf(nW2[j]);
    } else if (i < t1 + 2 * t2) {
        const int j = i - t1 - t2;
        const int per = H * H;
        const int l = j / per;
        const int r = j - l * per;
        const int k = r / H;
        const int o = r % H;
        nW1tc[(size_t)l * H * 2 * H + o * 2 * H + k] =
            f2bf(nW1[(size_t)l * 2 * H * H + k * H + o]);
    } else {
        const int j = i - t1 - 2 * t2;
        const int per = (H + 1) * H;
        const int l = j / per;
        const int r = j - l * per;
        if (l >= t2 / (H * H)) return;  // l < L
        const int jj = r / H;  // 0..128
        const int o = r % H;
        const float* w1 = nW1 + (size_t)l * 2 * H * H + (size_t)H * H;
        const float* row = (jj < H) ? (eW2 + (size_t)l * H * H + (size_t)jj * H)
                                    : (eb2 + (size_t)l * H);
        float s = 0.f;
#pragma unroll 4
        for (int c = 0; c < H; ++c) s = fmaf(row[c], w1[(size_t)c * H + o], s);
        if (jj < H)
            nW1tc[(size_t)l * H * 2 * H + o * 2 * H + H + jj] = f2bf(s);
        else
            cvec[(size_t)l * H + o] = s;
    }
}

// ----------------------- sort-by-dst machinery ----------------------------
__global__ __launch_bounds__(NTHR) void deg_kernel(const int* __restrict__ dst,
                                                   int* __restrict__ deg, int E) {
    const int e = blockIdx.x * NTHR + threadIdx.x;
    if (e < E) atomicAdd(&deg[dst[e]], 1);
}

__global__ __launch_bounds__(1024) void scan1_kernel(
    const int* __restrict__ deg, int* __restrict__ out,
    int* __restrict__ bsum, int N) {
    __shared__ int buf[1024];
    const int t = threadIdx.x;
    const int i = blockIdx.x * 1024 + t;
    const int x = (i < N) ? deg[i] : 0;
    buf[t] = x;
    __syncthreads();
    int v = x;
    for (int off = 1; off < 1024; off <<= 1) {
        const int y = (t >= off) ? buf[t - off] : 0;
        __syncthreads();
        v += y;
        buf[t] = v;
        __syncthreads();
    }
    if (i < N) out[i] = v - x;  // block-local exclusive
    if (t == 1023) bsum[blockIdx.x] = v;
}

__global__ void scan2_kernel(int* __restrict__ bsum, int nb) {
    if (threadIdx.x == 0) {
        int acc = 0;
        for (int i = 0; i < nb; ++i) {
            const int t = bsum[i];
            bsum[i] = acc;
            acc += t;
        }
    }
}

__global__ __launch_bounds__(NTHR) void scan3_kernel(
    int* __restrict__ out, int* __restrict__ cursor,
    const int* __restrict__ bsum, int* __restrict__ chunkLo, int N, int E,
    int numChunks) {
    const int i = blockIdx.x * NTHR + threadIdx.x;
    if (i < N) {
        const int v = out[i] + bsum[i >> 10];
        out[i] = v;
        cursor[i] = v;
    } else if (i == N) {
        out[N] = E;
    }
    if (i < numChunks) chunkLo[i] = 0x7fffffff;
}

// merged: chunkLo atomicMin + dst-sorted scatter
// srcS holds BYTE offsets into A (src * H * 2)
__global__ __launch_bounds__(NTHR) void finalize_kernel(
    const int* __restrict__ rowStart, int* __restrict__ chunkLo,
    const int* __restrict__ src, const int* __restrict__ dst,
    int* __restrict__ cursor, int* __restrict__ srcS, int N, int E) {
    const int i = blockIdx.x * NTHR + threadIdx.x;
    if (i < N) atomicMin(&chunkLo[rowStart[i] / CHUNK], i);
    if (i < E) {
        const int pos = atomicAdd(&cursor[dst[i]], 1);
        srcS[pos] = src[i] << 8;  // * 256 bytes per A row
    }
}

// ---------------- fp32 helper for encoder/decoder -------------------------
template <int K4>
__device__ __forceinline__ void mlp_layer(const float* __restrict__ W,
                                          const float* lds, int ldsStride,
                                          int c0, int egBase,
                                          float a0[8], float a1[8]) {
#pragma unroll 2
    for (int k4 = 0; k4 < K4; ++k4) {
        const float w00 = W[(k4 * 4 + 0) * H + c0];
        const float w01 = W[(k4 * 4 + 1) * H + c0];
        const float w02 = W[(k4 * 4 + 2) * H + c0];
        const float w03 = W[(k4 * 4 + 3) * H + c0];
        const float w10 = W[(k4 * 4 + 0) * H + c0 + 64];
        const float w11 = W[(k4 * 4 + 1) * H + c0 + 64];
        const float w12 = W[(k4 * 4 + 2) * H + c0 + 64];
        const float w13 = W[(k4 * 4 + 3) * H + c0 + 64];
#pragma unroll
        for (int e = 0; e < 8; ++e) {
            const float4 x = *reinterpret_cast<const float4*>(
                &lds[(egBase + e) * ldsStride + k4 * 4]);
            a0[e] = fmaf(x.x, w00, a0[e]);
            a0[e] = fmaf(x.y, w01, a0[e]);
            a0[e] = fmaf(x.z, w02, a0[e]);
            a0[e] = fmaf(x.w, w03, a0[e]);
            a1[e] = fmaf(x.x, w10, a1[e]);
            a1[e] = fmaf(x.y, w11, a1[e]);
            a1[e] = fmaf(x.z, w12, a1[e]);
            a1[e] = fmaf(x.w, w13, a1[e]);
        }
    }
}

// ---- FUSED encode+ab (32-row tile): nf -> h,h_bf; h_bf (LDS) -> A,B ------
__global__ __launch_bounds__(NTHR) void encab_kernel(
    const float* __restrict__ nf, const float* __restrict__ W1,
    const float* __restrict__ b1, const float* __restrict__ W2,
    const float* __restrict__ b2, float* __restrict__ h,
    unsigned short* __restrict__ h_bf,
    const unsigned short* __restrict__ eW1t,  // layer 0, [128 col][256 k]
    const float* __restrict__ eb1, unsigned short* __restrict__ A,
    float* __restrict__ Bout, int N) {
    __shared__ float xin[TILE * 16];                          // 2KB
    __shared__ float hm[TILE * H];                            // 16KB
    __shared__ __align__(16) unsigned short X[TILE * H];      // 8KB swizzled
    const int t = threadIdx.x;
    const int lane = t & 63;
    const int w = t >> 6;
    const int n0 = blockIdx.x * TILE;
    const int c0 = t & 63;
    const int eg = t >> 6;
    const int l15 = lane & 15;
    const int lq = lane >> 4;

    // ---- encode ----
    for (int i = t; i < TILE * 16; i += NTHR) {
        const int gi = n0 * 16 + i;
        xin[i] = (gi < N * 16) ? nf[gi] : 0.f;
    }
    __syncthreads();

    float a0[8], a1[8];
#pragma unroll
    for (int e = 0; e < 8; ++e) { a0[e] = 0.f; a1[e] = 0.f; }
    mlp_layer<4>(W1, xin, 16, c0, eg * 8, a0, a1);
    {
        const float bb0 = b1[c0], bb1 = b1[c0 + 64];
#pragma unroll
        for (int e = 0; e < 8; ++e) {
            hm[(eg * 8 + e) * H + c0] = gelu_fast(a0[e] + bb0);
            hm[(eg * 8 + e) * H + c0 + 64] = gelu_fast(a1[e] + bb1);
        }
    }
    __syncthreads();
#pragma unroll
    for (int e = 0; e < 8; ++e) { a0[e] = 0.f; a1[e] = 0.f; }
    mlp_layer<32>(W2, hm, H, c0, eg * 8, a0, a1);
    {
        const float bb0 = b2[c0], bb1 = b2[c0 + 64];
#pragma unroll
        for (int e = 0; e < 8; ++e) {
            const int row = eg * 8 + e;
            const int n = n0 + row;
            unsigned short hb0 = 0, hb1 = 0;
            if (n < N) {
                const float v0 = a0[e] + bb0, v1 = a1[e] + bb1;
                h[(size_t)n * H + c0] = v0;
                h[(size_t)n * H + c0 + 64] = v1;
                hb0 = f2bf(v0);
                hb1 = f2bf(v1);
                h_bf[(size_t)n * H + c0] = hb0;
                h_bf[(size_t)n * H + c0 + 64] = hb1;
            }
            const int bo0 = row * 256 + ((c0 * 2) ^ ((row & 7) << 4));
            const int bo1 = row * 256 + (((c0 + 64) * 2) ^ ((row & 7) << 4));
            *reinterpret_cast<unsigned short*>(reinterpret_cast<char*>(X) + bo0) = hb0;
            *reinterpret_cast<unsigned short*>(reinterpret_cast<char*>(X) + bo1) = hb1;
        }
    }

    // ---- ab (32 rows) ----
    const int half = w >> 1;  // 0 -> A (k 0..127), 1 -> B (k 128..255)
    const int cbase = (w & 1) * 64;
    bf16x8 Bf[4][4];
#pragma unroll
    for (int cg = 0; cg < 4; ++cg) {
        const int col = cbase + cg * 16 + l15;
#pragma unroll
        for (int s = 0; s < 4; ++s)
            Bf[cg][s] = *reinterpret_cast<const bf16x8*>(
                eW1t + (size_t)col * 256 + half * 128 + s * 32 + lq * 8);
    }
    __syncthreads();

    f32x4 acc[2][4];
#pragma unroll
    for (int rg = 0; rg < 2; ++rg)
#pragma unroll
        for (int cg = 0; cg < 4; ++cg) acc[rg][cg] = (f32x4)0.f;

#pragma unroll
    for (int s = 0; s < 4; ++s) {
        bf16x8 a[2];
#pragma unroll
        for (int rg = 0; rg < 2; ++rg) {
            const int row = rg * 16 + l15;
            const int byteoff = row * 256 + ((s * 64 + lq * 16) ^ ((row & 7) << 4));
            a[rg] = *reinterpret_cast<const bf16x8*>(
                reinterpret_cast<const char*>(X) + byteoff);
        }
#pragma unroll
        for (int rg = 0; rg < 2; ++rg)
#pragma unroll
            for (int cg = 0; cg < 4; ++cg)
                acc[rg][cg] = __builtin_amdgcn_mfma_f32_16x16x32_bf16(
                    a[rg], Bf[cg][s], acc[rg][cg], 0, 0, 0);
    }

#pragma unroll
    for (int cg = 0; cg < 4; ++cg) {
        const int col = cbase + cg * 16 + l15;
        const float bb = (half == 1) ? eb1[col] : 0.f;
#pragma unroll
        for (int rg = 0; rg < 2; ++rg) {
#pragma unroll
            for (int r = 0; r < 4; ++r) {
                const int row = rg * 16 + lq * 4 + r;
                const int n = n0 + row;
                if (n < N) {
                    if (half == 0)
                        A[(size_t)n * H + col] = f2bf(acc[rg][cg][r]);
                    else
                        Bout[(size_t)n * H + col] = acc[rg][cg][r] + bb;
                }
            }
        }
    }
}

// ---- edge gather: one wave per chunk, 2 cols/lane, 8-edge ILP window -----
__global__ __launch_bounds__(NTHR) void edge_gather_kernel(
    const unsigned short* __restrict__ A, const float* __restrict__ B,
    const int* __restrict__ srcS, const int* __restrict__ rowStart,  // N+1
    const int* __restrict__ chunkLo, unsigned short* __restrict__ aggB,
    int N, int E) {
    const int lane = threadIdx.x & 63;
    const int c = blockIdx.x * 4 + (threadIdx.x >> 6);
    const int nWaves = E / CHUNK + 1;
    if (c >= nWaves) return;
    int n = chunkLo[c];
    if (n >= N) return;  // sentinel: no node starts in this chunk
    const int Wend = (c + 1) * CHUNK;
    const int c2 = lane * 2;
    const char* Abase = (const char*)A + (size_t)(lane * 4);
    int r0 = rowStart[n];
    while (true) {
        const int r1 = rowStart[n + 1];
        const float2 bv = *reinterpret_cast<const float2*>(B + (size_t)n * H + c2);
        float s0 = 0.f, s1 = 0.f;
        int e = r0;
        for (; e + 8 <= r1; e += 8) {
            const int sa = srcS[e];
            const int sb = srcS[e + 1];
            const int sc = srcS[e + 2];
            const int sd = srcS[e + 3];
            const int se = srcS[e + 4];
            const int sf = srcS[e + 5];
            const int sg = srcS[e + 6];
            const int sh = srcS[e + 7];
            const unsigned int va = *reinterpret_cast<const unsigned int*>(Abase + sa);
            const unsigned int vb = *reinterpret_cast<const unsigned int*>(Abase + sb);
            const unsigned int vc = *reinterpret_cast<const unsigned int*>(Abase + sc);
            const unsigned int vd = *reinterpret_cast<const unsigned int*>(Abase + sd);
            const unsigned int ve = *reinterpret_cast<const unsigned int*>(Abase + se);
            const unsigned int vf = *reinterpret_cast<const unsigned int*>(Abase + sf);
            const unsigned int vg = *reinterpret_cast<const unsigned int*>(Abase + sg);
            const unsigned int vh = *reinterpret_cast<const unsigned int*>(Abase + sh);
            s0 += gelu_fast(bf2f_lo(va) + bv.x);
            s1 += gelu_fast(bf2f_hi(va) + bv.y);
            s0 += gelu_fast(bf2f_lo(vb) + bv.x);
            s1 += gelu_fast(bf2f_hi(vb) + bv.y);
            s0 += gelu_fast(bf2f_lo(vc) + bv.x);
            s1 += gelu_fast(bf2f_hi(vc) + bv.y);
            s0 += gelu_fast(bf2f_lo(vd) + bv.x);
            s1 += gelu_fast(bf2f_hi(vd) + bv.y);
            s0 += gelu_fast(bf2f_lo(ve) + bv.x);
            s1 += gelu_fast(bf2f_hi(ve) + bv.y);
            s0 += gelu_fast(bf2f_lo(vf) + bv.x);
            s1 += gelu_fast(bf2f_hi(vf) + bv.y);
            s0 += gelu_fast(bf2f_lo(vg) + bv.x);
            s1 += gelu_fast(bf2f_hi(vg) + bv.y);
            s0 += gelu_fast(bf2f_lo(vh) + bv.x);
            s1 += gelu_fast(bf2f_hi(vh) + bv.y);
        }
        for (; e + 4 <= r1; e += 4) {
            const int sa = srcS[e];
            const int sb = srcS[e + 1];
            const int sc = srcS[e + 2];
            const int sd = srcS[e + 3];
            const unsigned int va = *reinterpret_cast<const unsigned int*>(Abase + sa);
            const unsigned int vb = *reinterpret_cast<const unsigned int*>(Abase + sb);
            const unsigned int vc = *reinterpret_cast<const unsigned int*>(Abase + sc);
            const unsigned int vd = *reinterpret_cast<const unsigned int*>(Abase + sd);
            s0 += gelu_fast(bf2f_lo(va) + bv.x);
            s1 += gelu_fast(bf2f_hi(va) + bv.y);
            s0 += gelu_fast(bf2f_lo(vb) + bv.x);
            s1 += gelu_fast(bf2f_hi(vb) + bv.y);
            s0 += gelu_fast(bf2f_lo(vc) + bv.x);
            s1 += gelu_fast(bf2f_hi(vc) + bv.y);
            s0 += gelu_fast(bf2f_lo(vd) + bv.x);
            s1 += gelu_fast(bf2f_hi(vd) + bv.y);
        }
        for (; e < r1; ++e) {
            const unsigned int av =
                *reinterpret_cast<const unsigned int*>(Abase + srcS[e]);
            s0 += gelu_fast(bf2f_lo(av) + bv.x);
            s1 += gelu_fast(bf2f_hi(av) + bv.y);
        }
        const unsigned int packed =
            (unsigned int)f2bf(s0) | ((unsigned int)f2bf(s1) << 16);
        *reinterpret_cast<unsigned int*>(aggB + (size_t)n * H + c2) = packed;
        if (++n >= N) break;
        r0 = r1;
        if (r0 >= Wend) break;
    }
}

// ---- fused node update (+ next-layer A/B production | + decode on last) --
// h += MLP([h | aggB]; W1'=[nW1_top;Wcomb], b1'=b1+deg*cvec); refresh h_bf.
// PROD: A_out = h_new@eW1_top(next), B_out = h_new@eW1_bot(next)+eb1(next).
// !PROD (last layer): decode fused — h_new fp32 via LDS, 2x32-row decode MLP.
template <bool PROD>
__global__ __launch_bounds__(NTHR) void node_fused_kernel(
    float* __restrict__ h, unsigned short* __restrict__ h_bf,
    const unsigned short* __restrict__ aggB, const int* __restrict__ deg,
    const unsigned short* __restrict__ W1tc, const float* __restrict__ b1,
    const float* __restrict__ cvec, const unsigned short* __restrict__ W2t,
    const float* __restrict__ b2, const unsigned short* __restrict__ eW1tN,
    const float* __restrict__ eb1N, unsigned short* __restrict__ A_out,
    float* __restrict__ B_out, const float* __restrict__ dW1,
    const float* __restrict__ db1, const float* __restrict__ dW2,
    const float* __restrict__ db2, float* __restrict__ outp, int N) {
    __shared__ __align__(16) unsigned short X[TE * 256];  // 32KB
    __shared__ int degS[TE];
    const int t = threadIdx.x;
    const int lane = t & 63;
    const int w = t >> 6;
    const int n0 = blockIdx.x * TE;
    const int l15 = lane & 15;
    const int lq = lane >> 4;

    if (t < TE) degS[t] = (n0 + t < N) ? deg[n0 + t] : 0;
#pragma unroll
    for (int i = 0; i < 8; ++i) {
        const int c = i * NTHR + t;
        const int row = c >> 5;
        const int col8 = c & 31;
        const int n = n0 + row;
        int4 v = make_int4(0, 0, 0, 0);
        if (n < N) {
            const unsigned short* srcp = (col8 < 16) ? h_bf : aggB;
            v = *reinterpret_cast<const int4*>(srcp + (size_t)n * H +
                                               (col8 & 15) * 8);
        }
        const int byteoff = row * 512 + ((col8 * 16) ^ ((row & 7) << 4));
        *reinterpret_cast<int4*>(reinterpret_cast<char*>(X) + byteoff) = v;
    }

    bf16x8 B1[2][8];
#pragma unroll
    for (int cg = 0; cg < 2; ++cg) {
        const int col = w * 32 + cg * 16 + l15;
#pragma unroll
        for (int s = 0; s < 8; ++s)
            B1[cg][s] = *reinterpret_cast<const bf16x8*>(
                W1tc + (size_t)col * 256 + s * 32 + lq * 8);
    }
    __syncthreads();

    f32x4 acc[4][2];
#pragma unroll
    for (int rg = 0; rg < 4; ++rg)
#pragma unroll
        for (int cg = 0; cg < 2; ++cg) acc[rg][cg] = (f32x4)0.f;

#pragma unroll
    for (int s = 0; s < 8; ++s) {
        bf16x8 a[4];
#pragma unroll
        for (int rg = 0; rg < 4; ++rg) {
            const int row = rg * 16 + l15;
            const int byteoff = row * 512 + ((s * 64 + lq * 16) ^ ((row & 7) << 4));
            a[rg] = *reinterpret_cast<const bf16x8*>(
                reinterpret_cast<const char*>(X) + byteoff);
        }
#pragma unroll
        for (int rg = 0; rg < 4; ++rg)
#pragma unroll
            for (int cg = 0; cg < 2; ++cg)
                acc[rg][cg] = __builtin_amdgcn_mfma_f32_16x16x32_bf16(
                    a[rg], B1[cg][s], acc[rg][cg], 0, 0, 0);
    }
    __syncthreads();

    // L1 epilogue: gelu(acc + b1 + deg*cvec) -> hm (LDS bytes 0..16K)
#pragma unroll
    for (int cg = 0; cg < 2; ++cg) {
        const int col = w * 32 + cg * 16 + l15;
        const float bb = b1[col];
        const float cc = cvec[col];
#pragma unroll
        for (int rg = 0; rg < 4; ++rg) {
#pragma unroll
            for (int r = 0; r < 4; ++r) {
                const int row = rg * 16 + lq * 4 + r;
                const float v =
                    gelu_fast(acc[rg][cg][r] + bb + (float)degS[row] * cc);
                const int byteoff = row * 256 + ((col * 2) ^ ((row & 7) << 4));
                *reinterpret_cast<unsigned short*>(
                    reinterpret_cast<char*>(X) + byteoff) = f2bf(v);
            }
        }
    }

    bf16x8 B2[2][4];
#pragma unroll
    for (int cg = 0; cg < 2; ++cg) {
        const int col = w * 32 + cg * 16 + l15;
#pragma unroll
        for (int s = 0; s < 4; ++s)
            B2[cg][s] = *reinterpret_cast<const bf16x8*>(
                W2t + (size_t)col * 128 + s * 32 + lq * 8);
    }
    __syncthreads();

    f32x4 acc2[4][2];
#pragma unroll
    for (int rg = 0; rg < 4; ++rg)
#pragma unroll
        for (int cg = 0; cg < 2; ++cg) acc2[rg][cg] = (f32x4)0.f;

#pragma unroll
    for (int s = 0; s < 4; ++s) {
        bf16x8 a[4];
#pragma unroll
        for (int rg = 0; rg < 4; ++rg) {
            const int row = rg * 16 + l15;
            const int byteoff = row * 256 + ((s * 64 + lq * 16) ^ ((row & 7) << 4));
            a[rg] = *reinterpret_cast<const bf16x8*>(
                reinterpret_cast<const char*>(X) + byteoff);
        }
#pragma unroll
        for (int rg = 0; rg < 4; ++rg)
#pragma unroll
            for (int cg = 0; cg < 2; ++cg)
                acc2[rg][cg] = __builtin_amdgcn_mfma_f32_16x16x32_bf16(
                    a[rg], B2[cg][s], acc2[rg][cg], 0, 0, 0);
    }

    if (!PROD) __syncthreads();  // all hm reads done before fp32 overlay

    // residual write: h += update; refresh h_bf;
    // PROD: h_new bf16 -> LDS @16KB.  !PROD: h_new fp32 -> LDS (full X).
    float* Xf = reinterpret_cast<float*>(X);
#pragma unroll
    for (int cg = 0; cg < 2; ++cg) {
        const int col = w * 32 + cg * 16 + l15;
        const float bb = b2[col];
#pragma unroll
        for (int rg = 0; rg < 4; ++rg) {
#pragma unroll
            for (int r = 0; r < 4; ++r) {
                const int row = rg * 16 + lq * 4 + r;
                const int n = n0 + row;
                if (n < N) {
                    const float hv = h[(size_t)n * H + col] + acc2[rg][cg][r] + bb;
                    h[(size_t)n * H + col] = hv;
                    const unsigned short hb = f2bf(hv);
                    h_bf[(size_t)n * H + col] = hb;
                    if (PROD) {
                        const int byteoff =
                            16384 + row * 256 + ((col * 2) ^ ((row & 7) << 4));
                        *reinterpret_cast<unsigned short*>(
                            reinterpret_cast<char*>(X) + byteoff) = hb;
                    } else {
                        Xf[row * H + col] = hv;
                    }
                } else if (PROD) {
                    const int byteoff =
                        16384 + row * 256 + ((col * 2) ^ ((row & 7) << 4));
                    *reinterpret_cast<unsigned short*>(
                        reinterpret_cast<char*>(X) + byteoff) = 0;
                } else {
                    Xf[row * H + col] = 0.f;
                }
            }
        }
    }

    if constexpr (PROD) {
        bf16x8 B3[2][4], B4[2][4];
#pragma unroll
        for (int cg = 0; cg < 2; ++cg) {
            const int col = w * 32 + cg * 16 + l15;
#pragma unroll
            for (int s = 0; s < 4; ++s) {
                B3[cg][s] = *reinterpret_cast<const bf16x8*>(
                    eW1tN + (size_t)col * 256 + s * 32 + lq * 8);
                B4[cg][s] = *reinterpret_cast<const bf16x8*>(
                    eW1tN + (size_t)col * 256 + 128 + s * 32 + lq * 8);
            }
        }
        __syncthreads();

        f32x4 acc3[4][2], acc4[4][2];
#pragma unroll
        for (int rg = 0; rg < 4; ++rg)
#pragma unroll
            for (int cg = 0; cg < 2; ++cg) {
                acc3[rg][cg] = (f32x4)0.f;
                acc4[rg][cg] = (f32x4)0.f;
            }

#pragma unroll
        for (int s = 0; s < 4; ++s) {
            bf16x8 a[4];
#pragma unroll
            for (int rg = 0; rg < 4; ++rg) {
                const int row = rg * 16 + l15;
                const int byteoff =
                    16384 + row * 256 + ((s * 64 + lq * 16) ^ ((row & 7) << 4));
                a[rg] = *reinterpret_cast<const bf16x8*>(
                    reinterpret_cast<const char*>(X) + byteoff);
            }
#pragma unroll
            for (int rg = 0; rg < 4; ++rg)
#pragma unroll
                for (int cg = 0; cg < 2; ++cg) {
                    acc3[rg][cg] = __builtin_amdgcn_mfma_f32_16x16x32_bf16(
                        a[rg], B3[cg][s], acc3[rg][cg], 0, 0, 0);
                    acc4[rg][cg] = __builtin_amdgcn_mfma_f32_16x16x32_bf16(
                        a[rg], B4[cg][s], acc4[rg][cg], 0, 0, 0);
                }
        }

#pragma unroll
        for (int cg = 0; cg < 2; ++cg) {
            const int col = w * 32 + cg * 16 + l15;
            const float bb = eb1N[col];
#pragma unroll
            for (int rg = 0; rg < 4; ++rg) {
#pragma unroll
                for (int r = 0; r < 4; ++r) {
                    const int row = rg * 16 + lq * 4 + r;
                    const int n = n0 + row;
                    if (n < N) {
                        A_out[(size_t)n * H + col] = f2bf(acc3[rg][cg][r]);
                        B_out[(size_t)n * H + col] = acc4[rg][cg][r] + bb;
                    }
                }
            }
        }
    } else {
        // ---- fused decode on this block's 64 rows (2 halves of 32) ----
        // Math verbatim from decode_kernel (fp32) on identical hv values.
        __shared__ float hm2[32 * 132];  // 16.9KB (only in !PROD instantiation)
        __syncthreads();                 // Xf fully written
        const int c0 = t & 63;
        const int eg = t >> 6;
#pragma unroll 1
        for (int halfT = 0; halfT < 2; ++halfT) {
            float a0[8], a1[8];
#pragma unroll
            for (int e = 0; e < 8; ++e) { a0[e] = 0.f; a1[e] = 0.f; }
            mlp_layer<32>(dW1, Xf + halfT * 32 * H, H, c0, eg * 8, a0, a1);
            {
                const float bb0 = db1[c0], bb1 = db1[c0 + 64];
#pragma unroll
                for (int e = 0; e < 8; ++e) {
                    hm2[(eg * 8 + e) * 132 + c0] = gelu_fast(a0[e] + bb0);
                    hm2[(eg * 8 + e) * 132 + c0 + 64] = gelu_fast(a1[e] + bb1);
                }
            }
            __syncthreads();
            {
                const int e = t >> 3;  // 0..31
                const int o = t & 7;
                const int n = n0 + halfT * 32 + e;
                float accd = db2[o];
#pragma unroll 4
                for (int k = 0; k < H; ++k)
                    accd = fmaf(hm2[e * 132 + k], dW2[k * 8 + o], accd);
                if (n < N) outp[(size_t)n * 8 + o] = accd;
            }
            __syncthreads();  // hm2 reuse for next half
        }
    }
}

extern "C" void kernel_launch(void* const* d_in, const int* in_sizes, int n_in,
                              void* d_out, int out_size, void* d_ws,
                              size_t ws_size, hipStream_t stream) {
    (void)n_in; (void)out_size; (void)ws_size;
    const float* nf      = (const float*)d_in[0];
    const int*   ei      = (const int*)d_in[1];
    const float* enc_W1  = (const float*)d_in[2];
    const float* enc_b1  = (const float*)d_in[3];
    const float* enc_W2  = (const float*)d_in[4];
    const float* enc_b2  = (const float*)d_in[5];
    const float* edge_W1 = (const float*)d_in[6];
    const float* edge_b1 = (const float*)d_in[7];
    const float* edge_W2 = (const float*)d_in[8];
    const float* edge_b2 = (const float*)d_in[9];
    const float* node_W1 = (const float*)d_in[10];
    const float* node_b1 = (const float*)d_in[11];
    const float* node_W2 = (const float*)d_in[12];
    const float* node_b2 = (const float*)d_in[13];
    const float* dec_W1  = (const float*)d_in[14];
    const float* dec_b1  = (const float*)d_in[15];
    const float* dec_W2  = (const float*)d_in[16];
    const float* dec_b2  = (const float*)d_in[17];

    const int N = in_sizes[0] / 16;
    const int E = in_sizes[1] / 2;
    const int L = in_sizes[7] / H;  // edge_b1 is [L,H]
    const int numChunks = E / CHUNK + 1;

    // ---------------- workspace layout ----------------
    char* ws = (char*)d_ws;
    float* h    = (float*)ws;                    ws += (size_t)N * H * 4;
    float* Bf32 = (float*)ws;                    ws += (size_t)N * H * 4;
    unsigned short* h_bf = (unsigned short*)ws;  ws += (size_t)N * H * 2;
    unsigned short* A_bf = (unsigned short*)ws;  ws += (size_t)N * H * 2;
    unsigned short* aggB = (unsigned short*)ws;  ws += (size_t)N * H * 2;
    int* srcS     = (int*)ws;                    ws += (size_t)E * 4;
    int* deg      = (int*)ws;                    ws += (size_t)N * 4;
    int* rowStart = (int*)ws;                    ws += (size_t)(N + 1) * 4;
    int* cursor   = (int*)ws;                    ws += (size_t)N * 4;
    int* bsum     = (int*)ws;                    ws += (size_t)256 * 4;
    int* chunkLo  = (int*)ws;                    ws += (size_t)numChunks * 4;
    unsigned short* eW1t = (unsigned short*)ws;  ws += (size_t)L * 2 * H * H * 2;
    unsigned short* nW1tc = (unsigned short*)ws; ws += (size_t)L * 2 * H * H * 2;
    unsigned short* nW2t = (unsigned short*)ws;  ws += (size_t)L * H * H * 2;
    float* cvec   = (float*)ws;                  ws += (size_t)L * H * 4;

    const int* srcArr = ei;
    const int* dstArr = ei + E;

    // ---- merged weight prep + wcomb + deg zeroing (one dispatch) ----
    {
        const int t1 = L * 2 * H * H, t2 = L * H * H;
        const int total = t1 + 2 * t2 + L * (H + 1) * H;
        prep_kernel<<<(total + NTHR - 1) / NTHR, NTHR, 0, stream>>>(
            edge_W1, node_W2, node_W1, edge_W2, edge_b2, eW1t, nW2t, nW1tc,
            cvec, deg, t1, t2, N);
    }

    // ---- sort edges by dst (hist + multiblock scan + merged finalize) ----
    deg_kernel<<<(E + NTHR - 1) / NTHR, NTHR, 0, stream>>>(dstArr, deg, E);
    const int nScanB = (N + 1023) / 1024;
    scan1_kernel<<<nScanB, 1024, 0, stream>>>(deg, rowStart, bsum, N);
    scan2_kernel<<<1, 64, 0, stream>>>(bsum, nScanB);
    const int scan3Span = (N + 1 > numChunks) ? (N + 1) : numChunks;
    scan3_kernel<<<(scan3Span + NTHR - 1) / NTHR, NTHR, 0, stream>>>(
        rowStart, cursor, bsum, chunkLo, N, E, numChunks);
    const int finSpan = (N > E) ? N : E;
    finalize_kernel<<<(finSpan + NTHR - 1) / NTHR, NTHR, 0, stream>>>(
        rowStart, chunkLo, srcArr, dstArr, cursor, srcS, N, E);

    const int encBlocks  = (N + TILE - 1) / TILE;
    const int nodeBlocks = (N + TE - 1) / TE;
    const int gatherBlks = (numChunks + 3) / 4;

    // fused encode + layer-0 A/B production
    encab_kernel<<<encBlocks, NTHR, 0, stream>>>(
        nf, enc_W1, enc_b1, enc_W2, enc_b2, h, h_bf, eW1t, edge_b1, A_bf,
        Bf32, N);
    for (int l = 0; l < L; ++l) {
        edge_gather_kernel<<<gatherBlks, NTHR, 0, stream>>>(
            A_bf, Bf32, srcS, rowStart, chunkLo, aggB, N, E);
        if (l + 1 < L) {
            node_fused_kernel<true><<<nodeBlocks, NTHR, 0, stream>>>(
                h, h_bf, aggB, deg, nW1tc + (size_t)l * 2 * H * H,
                node_b1 + (size_t)l * H, cvec + (size_t)l * H,
                nW2t + (size_t)l * H * H, node_b2 + (size_t)l * H,
                eW1t + (size_t)(l + 1) * 2 * H * H,
                edge_b1 + (size_t)(l + 1) * H, A_bf, Bf32, nullptr, nullptr,
                nullptr, nullptr, nullptr, N);
        } else {
            node_fused_kernel<false><<<nodeBlocks, NTHR, 0, stream>>>(
                h, h_bf, aggB, deg, nW1tc + (size_t)l * 2 * H * H,
                node_b1 + (size_t)l * H, cvec + (size_t)l * H,
                nW2t + (size_t)l * H * H, node_b2 + (size_t)l * H, nullptr,
                nullptr, nullptr, nullptr, dec_W1, dec_b1, dec_W2, dec_b2,
                (float*)d_out, N);
        }
    }
}

// Round 16
// 676.836 us; speedup vs baseline: 1.0099x; 1.0008x over previous
//
#include <hip/hip_runtime.h>
#include <math.h>

// FieldlineGraphForecaster round 15: REVERT to r11 (measured best: 676us,
// absmax 64). r14's packed-pair gelu broke numerics (absmax 6000) — the
// gelu/erf value path is FROZEN (r6 and r14 both failed by touching it).
// Config: fused encab, node TE=64 (+next-layer A/B production), scalar
// 5-term-erf gather with 8-edge ILP window, merged prep/scan3/finalize.

constexpr int H = 128;
constexpr int NTHR = 256;
constexpr int TE = 64;    // rows per node MFMA tile
constexpr int TILE = 32;  // rows per enc/ab/dec tile
constexpr int CHUNK = 16; // sorted edges per chunk

using bf16x8 = __attribute__((ext_vector_type(8))) short;
using f32x4  = __attribute__((ext_vector_type(4))) float;

// Branchless GELU: A&S 7.1.26 erf (5-term), |eps|<=1.5e-7. DO NOT MODIFY:
// 3-term erf (r6) and packed-pair rewrite (r14) both failed the harness.
__device__ __forceinline__ float gelu_fast(float x) {
    const float u = fabsf(x) * 0.70710678118654752440f;
    const float t = __builtin_amdgcn_rcpf(fmaf(0.3275911f, u, 1.f));
    float p = fmaf(1.061405429f, t, -1.453152027f);
    p = fmaf(p, t, 1.421413741f);
    p = fmaf(p, t, -0.284496736f);
    p = fmaf(p, t, 0.254829592f);
    p = p * t;
    const float e = __expf(-u * u);
    float er = fmaf(-p, e, 1.f);  // erf(|x|/sqrt2)
    er = copysignf(er, x);
    return 0.5f * x * (1.f + er);
}

__device__ __forceinline__ unsigned short f2bf(float f) {
    unsigned int u = __builtin_bit_cast(unsigned int, f);
    u = (u + 0x7fffu + ((u >> 16) & 1u)) >> 16;
    return (unsigned short)u;
}

__device__ __forceinline__ float bf2f_lo(unsigned int v) {
    return __builtin_bit_cast(float, v << 16);
}
__device__ __forceinline__ float bf2f_hi(unsigned int v) {
    return __builtin_bit_cast(float, v & 0xffff0000u);
}

// ---- merged prep: eW1t, nW2t, nW1tc(top), wcomb(bottom+cvec), deg=0 ------
__global__ __launch_bounds__(NTHR) void prep_kernel(
    const float* __restrict__ eW1, const float* __restrict__ nW2,
    const float* __restrict__ nW1, const float* __restrict__ eW2,
    const float* __restrict__ eb2, unsigned short* __restrict__ eW1t,
    unsigned short* __restrict__ nW2t, unsigned short* __restrict__ nW1tc,
    float* __restrict__ cvec, int* __restrict__ deg, int t1, int t2, int N) {
    const int i = blockIdx.x * NTHR + threadIdx.x;
    if (i < N) deg[i] = 0;
    if (i < t1) {
        const int per = 2 * H * H;
        const int l = i / per;
        const int r = i - l * per;
        const int n = r % H;
        const int k = r / H;
        eW1t[(size_t)l * per + n * 2 * H + k] = f2bf(eW1[i]);
    } else if (i < t1 + t2) {
        const int j = i - t1;
        const int per = H * H;
        const int l = j / per;
        const int r = j - l * per;
        const int n = r % H;
        const int k = r / H;
        nW2t[(size_t)l * per + n * H + k] = f2bf(nW2[j]);
    } else if (i < t1 + 2 * t2) {
        const int j = i - t1 - t2;
        const int per = H * H;
        const int l = j / per;
        const int r = j - l * per;
        const int k = r / H;
        const int o = r % H;
        nW1tc[(size_t)l * H * 2 * H + o * 2 * H + k] =
            f2bf(nW1[(size_t)l * 2 * H * H + k * H + o]);
    } else {
        const int j = i - t1 - 2 * t2;
        const int per = (H + 1) * H;
        const int l = j / per;
        const int r = j - l * per;
        if (l >= t2 / (H * H)) return;  // l < L
        const int jj = r / H;  // 0..128
        const int o = r % H;
        const float* w1 = nW1 + (size_t)l * 2 * H * H + (size_t)H * H;
        const float* row = (jj < H) ? (eW2 + (size_t)l * H * H + (size_t)jj * H)
                                    : (eb2 + (size_t)l * H);
        float s = 0.f;
#pragma unroll 4
        for (int c = 0; c < H; ++c) s = fmaf(row[c], w1[(size_t)c * H + o], s);
        if (jj < H)
            nW1tc[(size_t)l * H * 2 * H + o * 2 * H + H + jj] = f2bf(s);
        else
            cvec[(size_t)l * H + o] = s;
    }
}

// ----------------------- sort-by-dst machinery ----------------------------
__global__ __launch_bounds__(NTHR) void deg_kernel(const int* __restrict__ dst,
                                                   int* __restrict__ deg, int E) {
    const int e = blockIdx.x * NTHR + threadIdx.x;
    if (e < E) atomicAdd(&deg[dst[e]], 1);
}

__global__ __launch_bounds__(1024) void scan1_kernel(
    const int* __restrict__ deg, int* __restrict__ out,
    int* __restrict__ bsum, int N) {
    __shared__ int buf[1024];
    const int t = threadIdx.x;
    const int i = blockIdx.x * 1024 + t;
    const int x = (i < N) ? deg[i] : 0;
    buf[t] = x;
    __syncthreads();
    int v = x;
    for (int off = 1; off < 1024; off <<= 1) {
        const int y = (t >= off) ? buf[t - off] : 0;
        __syncthreads();
        v += y;
        buf[t] = v;
        __syncthreads();
    }
    if (i < N) out[i] = v - x;  // block-local exclusive
    if (t == 1023) bsum[blockIdx.x] = v;
}

__global__ void scan2_kernel(int* __restrict__ bsum, int nb) {
    if (threadIdx.x == 0) {
        int acc = 0;
        for (int i = 0; i < nb; ++i) {
            const int t = bsum[i];
            bsum[i] = acc;
            acc += t;
        }
    }
}

__global__ __launch_bounds__(NTHR) void scan3_kernel(
    int* __restrict__ out, int* __restrict__ cursor,
    const int* __restrict__ bsum, int* __restrict__ chunkLo, int N, int E,
    int numChunks) {
    const int i = blockIdx.x * NTHR + threadIdx.x;
    if (i < N) {
        const int v = out[i] + bsum[i >> 10];
        out[i] = v;
        cursor[i] = v;
    } else if (i == N) {
        out[N] = E;
    }
    if (i < numChunks) chunkLo[i] = 0x7fffffff;
}

// merged: chunkLo atomicMin + dst-sorted scatter
// srcS holds BYTE offsets into A (src * H * 2)
__global__ __launch_bounds__(NTHR) void finalize_kernel(
    const int* __restrict__ rowStart, int* __restrict__ chunkLo,
    const int* __restrict__ src, const int* __restrict__ dst,
    int* __restrict__ cursor, int* __restrict__ srcS, int N, int E) {
    const int i = blockIdx.x * NTHR + threadIdx.x;
    if (i < N) atomicMin(&chunkLo[rowStart[i] / CHUNK], i);
    if (i < E) {
        const int pos = atomicAdd(&cursor[dst[i]], 1);
        srcS[pos] = src[i] << 8;  // * 256 bytes per A row
    }
}

// ---------------- fp32 helper for encoder/decoder -------------------------
template <int K4>
__device__ __forceinline__ void mlp_layer(const float* __restrict__ W,
                                          const float* lds, int ldsStride,
                                          int c0, int egBase,
                                          float a0[8], float a1[8]) {
#pragma unroll 2
    for (int k4 = 0; k4 < K4; ++k4) {
        const float w00 = W[(k4 * 4 + 0) * H + c0];
        const float w01 = W[(k4 * 4 + 1) * H + c0];
        const float w02 = W[(k4 * 4 + 2) * H + c0];
        const float w03 = W[(k4 * 4 + 3) * H + c0];
        const float w10 = W[(k4 * 4 + 0) * H + c0 + 64];
        const float w11 = W[(k4 * 4 + 1) * H + c0 + 64];
        const float w12 = W[(k4 * 4 + 2) * H + c0 + 64];
        const float w13 = W[(k4 * 4 + 3) * H + c0 + 64];
#pragma unroll
        for (int e = 0; e < 8; ++e) {
            const float4 x = *reinterpret_cast<const float4*>(
                &lds[(egBase + e) * ldsStride + k4 * 4]);
            a0[e] = fmaf(x.x, w00, a0[e]);
            a0[e] = fmaf(x.y, w01, a0[e]);
            a0[e] = fmaf(x.z, w02, a0[e]);
            a0[e] = fmaf(x.w, w03, a0[e]);
            a1[e] = fmaf(x.x, w10, a1[e]);
            a1[e] = fmaf(x.y, w11, a1[e]);
            a1[e] = fmaf(x.z, w12, a1[e]);
            a1[e] = fmaf(x.w, w13, a1[e]);
        }
    }
}

// ---- FUSED encode+ab (32-row tile): nf -> h,h_bf; h_bf (LDS) -> A,B ------
__global__ __launch_bounds__(NTHR) void encab_kernel(
    const float* __restrict__ nf, const float* __restrict__ W1,
    const float* __restrict__ b1, const float* __restrict__ W2,
    const float* __restrict__ b2, float* __restrict__ h,
    unsigned short* __restrict__ h_bf,
    const unsigned short* __restrict__ eW1t,  // layer 0, [128 col][256 k]
    const float* __restrict__ eb1, unsigned short* __restrict__ A,
    float* __restrict__ Bout, int N) {
    __shared__ float xin[TILE * 16];                          // 2KB
    __shared__ float hm[TILE * H];                            // 16KB
    __shared__ __align__(16) unsigned short X[TILE * H];      // 8KB swizzled
    const int t = threadIdx.x;
    const int lane = t & 63;
    const int w = t >> 6;
    const int n0 = blockIdx.x * TILE;
    const int c0 = t & 63;
    const int eg = t >> 6;
    const int l15 = lane & 15;
    const int lq = lane >> 4;

    // ---- encode ----
    for (int i = t; i < TILE * 16; i += NTHR) {
        const int gi = n0 * 16 + i;
        xin[i] = (gi < N * 16) ? nf[gi] : 0.f;
    }
    __syncthreads();

    float a0[8], a1[8];
#pragma unroll
    for (int e = 0; e < 8; ++e) { a0[e] = 0.f; a1[e] = 0.f; }
    mlp_layer<4>(W1, xin, 16, c0, eg * 8, a0, a1);
    {
        const float bb0 = b1[c0], bb1 = b1[c0 + 64];
#pragma unroll
        for (int e = 0; e < 8; ++e) {
            hm[(eg * 8 + e) * H + c0] = gelu_fast(a0[e] + bb0);
            hm[(eg * 8 + e) * H + c0 + 64] = gelu_fast(a1[e] + bb1);
        }
    }
    __syncthreads();
#pragma unroll
    for (int e = 0; e < 8; ++e) { a0[e] = 0.f; a1[e] = 0.f; }
    mlp_layer<32>(W2, hm, H, c0, eg * 8, a0, a1);
    {
        const float bb0 = b2[c0], bb1 = b2[c0 + 64];
#pragma unroll
        for (int e = 0; e < 8; ++e) {
            const int row = eg * 8 + e;
            const int n = n0 + row;
            unsigned short hb0 = 0, hb1 = 0;
            if (n < N) {
                const float v0 = a0[e] + bb0, v1 = a1[e] + bb1;
                h[(size_t)n * H + c0] = v0;
                h[(size_t)n * H + c0 + 64] = v1;
                hb0 = f2bf(v0);
                hb1 = f2bf(v1);
                h_bf[(size_t)n * H + c0] = hb0;
                h_bf[(size_t)n * H + c0 + 64] = hb1;
            }
            const int bo0 = row * 256 + ((c0 * 2) ^ ((row & 7) << 4));
            const int bo1 = row * 256 + (((c0 + 64) * 2) ^ ((row & 7) << 4));
            *reinterpret_cast<unsigned short*>(reinterpret_cast<char*>(X) + bo0) = hb0;
            *reinterpret_cast<unsigned short*>(reinterpret_cast<char*>(X) + bo1) = hb1;
        }
    }

    // ---- ab (32 rows) ----
    const int half = w >> 1;  // 0 -> A (k 0..127), 1 -> B (k 128..255)
    const int cbase = (w & 1) * 64;
    bf16x8 Bf[4][4];
#pragma unroll
    for (int cg = 0; cg < 4; ++cg) {
        const int col = cbase + cg * 16 + l15;
#pragma unroll
        for (int s = 0; s < 4; ++s)
            Bf[cg][s] = *reinterpret_cast<const bf16x8*>(
                eW1t + (size_t)col * 256 + half * 128 + s * 32 + lq * 8);
    }
    __syncthreads();

    f32x4 acc[2][4];
#pragma unroll
    for (int rg = 0; rg < 2; ++rg)
#pragma unroll
        for (int cg = 0; cg < 4; ++cg) acc[rg][cg] = (f32x4)0.f;

#pragma unroll
    for (int s = 0; s < 4; ++s) {
        bf16x8 a[2];
#pragma unroll
        for (int rg = 0; rg < 2; ++rg) {
            const int row = rg * 16 + l15;
            const int byteoff = row * 256 + ((s * 64 + lq * 16) ^ ((row & 7) << 4));
            a[rg] = *reinterpret_cast<const bf16x8*>(
                reinterpret_cast<const char*>(X) + byteoff);
        }
#pragma unroll
        for (int rg = 0; rg < 2; ++rg)
#pragma unroll
            for (int cg = 0; cg < 4; ++cg)
                acc[rg][cg] = __builtin_amdgcn_mfma_f32_16x16x32_bf16(
                    a[rg], Bf[cg][s], acc[rg][cg], 0, 0, 0);
    }

#pragma unroll
    for (int cg = 0; cg < 4; ++cg) {
        const int col = cbase + cg * 16 + l15;
        const float bb = (half == 1) ? eb1[col] : 0.f;
#pragma unroll
        for (int rg = 0; rg < 2; ++rg) {
#pragma unroll
            for (int r = 0; r < 4; ++r) {
                const int row = rg * 16 + lq * 4 + r;
                const int n = n0 + row;
                if (n < N) {
                    if (half == 0)
                        A[(size_t)n * H + col] = f2bf(acc[rg][cg][r]);
                    else
                        Bout[(size_t)n * H + col] = acc[rg][cg][r] + bb;
                }
            }
        }
    }
}

// ---- edge gather: one wave per chunk, 2 cols/lane, 8-edge ILP window -----
__global__ __launch_bounds__(NTHR) void edge_gather_kernel(
    const unsigned short* __restrict__ A, const float* __restrict__ B,
    const int* __restrict__ srcS, const int* __restrict__ rowStart,  // N+1
    const int* __restrict__ chunkLo, unsigned short* __restrict__ aggB,
    int N, int E) {
    const int lane = threadIdx.x & 63;
    const int c = blockIdx.x * 4 + (threadIdx.x >> 6);
    const int nWaves = E / CHUNK + 1;
    if (c >= nWaves) return;
    int n = chunkLo[c];
    if (n >= N) return;  // sentinel: no node starts in this chunk
    const int Wend = (c + 1) * CHUNK;
    const int c2 = lane * 2;
    const char* Abase = (const char*)A + (size_t)(lane * 4);
    int r0 = rowStart[n];
    while (true) {
        const int r1 = rowStart[n + 1];
        const float2 bv = *reinterpret_cast<const float2*>(B + (size_t)n * H + c2);
        float s0 = 0.f, s1 = 0.f;
        int e = r0;
        for (; e + 8 <= r1; e += 8) {
            const int sa = srcS[e];
            const int sb = srcS[e + 1];
            const int sc = srcS[e + 2];
            const int sd = srcS[e + 3];
            const int se = srcS[e + 4];
            const int sf = srcS[e + 5];
            const int sg = srcS[e + 6];
            const int sh = srcS[e + 7];
            const unsigned int va = *reinterpret_cast<const unsigned int*>(Abase + sa);
            const unsigned int vb = *reinterpret_cast<const unsigned int*>(Abase + sb);
            const unsigned int vc = *reinterpret_cast<const unsigned int*>(Abase + sc);
            const unsigned int vd = *reinterpret_cast<const unsigned int*>(Abase + sd);
            const unsigned int ve = *reinterpret_cast<const unsigned int*>(Abase + se);
            const unsigned int vf = *reinterpret_cast<const unsigned int*>(Abase + sf);
            const unsigned int vg = *reinterpret_cast<const unsigned int*>(Abase + sg);
            const unsigned int vh = *reinterpret_cast<const unsigned int*>(Abase + sh);
            s0 += gelu_fast(bf2f_lo(va) + bv.x);
            s1 += gelu_fast(bf2f_hi(va) + bv.y);
            s0 += gelu_fast(bf2f_lo(vb) + bv.x);
            s1 += gelu_fast(bf2f_hi(vb) + bv.y);
            s0 += gelu_fast(bf2f_lo(vc) + bv.x);
            s1 += gelu_fast(bf2f_hi(vc) + bv.y);
            s0 += gelu_fast(bf2f_lo(vd) + bv.x);
            s1 += gelu_fast(bf2f_hi(vd) + bv.y);
            s0 += gelu_fast(bf2f_lo(ve) + bv.x);
            s1 += gelu_fast(bf2f_hi(ve) + bv.y);
            s0 += gelu_fast(bf2f_lo(vf) + bv.x);
            s1 += gelu_fast(bf2f_hi(vf) + bv.y);
            s0 += gelu_fast(bf2f_lo(vg) + bv.x);
            s1 += gelu_fast(bf2f_hi(vg) + bv.y);
            s0 += gelu_fast(bf2f_lo(vh) + bv.x);
            s1 += gelu_fast(bf2f_hi(vh) + bv.y);
        }
        for (; e + 4 <= r1; e += 4) {
            const int sa = srcS[e];
            const int sb = srcS[e + 1];
            const int sc = srcS[e + 2];
            const int sd = srcS[e + 3];
            const unsigned int va = *reinterpret_cast<const unsigned int*>(Abase + sa);
            const unsigned int vb = *reinterpret_cast<const unsigned int*>(Abase + sb);
            const unsigned int vc = *reinterpret_cast<const unsigned int*>(Abase + sc);
            const unsigned int vd = *reinterpret_cast<const unsigned int*>(Abase + sd);
            s0 += gelu_fast(bf2f_lo(va) + bv.x);
            s1 += gelu_fast(bf2f_hi(va) + bv.y);
            s0 += gelu_fast(bf2f_lo(vb) + bv.x);
            s1 += gelu_fast(bf2f_hi(vb) + bv.y);
            s0 += gelu_fast(bf2f_lo(vc) + bv.x);
            s1 += gelu_fast(bf2f_hi(vc) + bv.y);
            s0 += gelu_fast(bf2f_lo(vd) + bv.x);
            s1 += gelu_fast(bf2f_hi(vd) + bv.y);
        }
        for (; e < r1; ++e) {
            const unsigned int av =
                *reinterpret_cast<const unsigned int*>(Abase + srcS[e]);
            s0 += gelu_fast(bf2f_lo(av) + bv.x);
            s1 += gelu_fast(bf2f_hi(av) + bv.y);
        }
        const unsigned int packed =
            (unsigned int)f2bf(s0) | ((unsigned int)f2bf(s1) << 16);
        *reinterpret_cast<unsigned int*>(aggB + (size_t)n * H + c2) = packed;
        if (++n >= N) break;
        r0 = r1;
        if (r0 >= Wend) break;
    }
}

// ---- fused node update (+ next-layer A/B production) ---------------------
template <bool PROD>
__global__ __launch_bounds__(NTHR) void node_fused_kernel(
    float* __restrict__ h, unsigned short* __restrict__ h_bf,
    const unsigned short* __restrict__ aggB, const int* __restrict__ deg,
    const unsigned short* __restrict__ W1tc, const float* __restrict__ b1,
    const float* __restrict__ cvec, const unsigned short* __restrict__ W2t,
    const float* __restrict__ b2, const unsigned short* __restrict__ eW1tN,
    const float* __restrict__ eb1N, unsigned short* __restrict__ A_out,
    float* __restrict__ B_out, int N) {
    __shared__ __align__(16) unsigned short X[TE * 256];  // 32KB
    __shared__ int degS[TE];
    const int t = threadIdx.x;
    const int lane = t & 63;
    const int w = t >> 6;
    const int n0 = blockIdx.x * TE;
    const int l15 = lane & 15;
    const int lq = lane >> 4;

    if (t < TE) degS[t] = (n0 + t < N) ? deg[n0 + t] : 0;
#pragma unroll
    for (int i = 0; i < 8; ++i) {
        const int c = i * NTHR + t;
        const int row = c >> 5;
        const int col8 = c & 31;
        const int n = n0 + row;
        int4 v = make_int4(0, 0, 0, 0);
        if (n < N) {
            const unsigned short* srcp = (col8 < 16) ? h_bf : aggB;
            v = *reinterpret_cast<const int4*>(srcp + (size_t)n * H +
                                               (col8 & 15) * 8);
        }
        const int byteoff = row * 512 + ((col8 * 16) ^ ((row & 7) << 4));
        *reinterpret_cast<int4*>(reinterpret_cast<char*>(X) + byteoff) = v;
    }

    bf16x8 B1[2][8];
#pragma unroll
    for (int cg = 0; cg < 2; ++cg) {
        const int col = w * 32 + cg * 16 + l15;
#pragma unroll
        for (int s = 0; s < 8; ++s)
            B1[cg][s] = *reinterpret_cast<const bf16x8*>(
                W1tc + (size_t)col * 256 + s * 32 + lq * 8);
    }
    __syncthreads();

    f32x4 acc[4][2];
#pragma unroll
    for (int rg = 0; rg < 4; ++rg)
#pragma unroll
        for (int cg = 0; cg < 2; ++cg) acc[rg][cg] = (f32x4)0.f;

#pragma unroll
    for (int s = 0; s < 8; ++s) {
        bf16x8 a[4];
#pragma unroll
        for (int rg = 0; rg < 4; ++rg) {
            const int row = rg * 16 + l15;
            const int byteoff = row * 512 + ((s * 64 + lq * 16) ^ ((row & 7) << 4));
            a[rg] = *reinterpret_cast<const bf16x8*>(
                reinterpret_cast<const char*>(X) + byteoff);
        }
#pragma unroll
        for (int rg = 0; rg < 4; ++rg)
#pragma unroll
            for (int cg = 0; cg < 2; ++cg)
                acc[rg][cg] = __builtin_amdgcn_mfma_f32_16x16x32_bf16(
                    a[rg], B1[cg][s], acc[rg][cg], 0, 0, 0);
    }
    __syncthreads();

    // L1 epilogue: gelu(acc + b1 + deg*cvec) -> hm (LDS bytes 0..16K)
#pragma unroll
    for (int cg = 0; cg < 2; ++cg) {
        const int col = w * 32 + cg * 16 + l15;
        const float bb = b1[col];
        const float cc = cvec[col];
#pragma unroll
        for (int rg = 0; rg < 4; ++rg) {
#pragma unroll
            for (int r = 0; r < 4; ++r) {
                const int row = rg * 16 + lq * 4 + r;
                const float v =
                    gelu_fast(acc[rg][cg][r] + bb + (float)degS[row] * cc);
                const int byteoff = row * 256 + ((col * 2) ^ ((row & 7) << 4));
                *reinterpret_cast<unsigned short*>(
                    reinterpret_cast<char*>(X) + byteoff) = f2bf(v);
            }
        }
    }

    bf16x8 B2[2][4];
#pragma unroll
    for (int cg = 0; cg < 2; ++cg) {
        const int col = w * 32 + cg * 16 + l15;
#pragma unroll
        for (int s = 0; s < 4; ++s)
            B2[cg][s] = *reinterpret_cast<const bf16x8*>(
                W2t + (size_t)col * 128 + s * 32 + lq * 8);
    }
    __syncthreads();

    f32x4 acc2[4][2];
#pragma unroll
    for (int rg = 0; rg < 4; ++rg)
#pragma unroll
        for (int cg = 0; cg < 2; ++cg) acc2[rg][cg] = (f32x4)0.f;

#pragma unroll
    for (int s = 0; s < 4; ++s) {
        bf16x8 a[4];
#pragma unroll
        for (int rg = 0; rg < 4; ++rg) {
            const int row = rg * 16 + l15;
            const int byteoff = row * 256 + ((s * 64 + lq * 16) ^ ((row & 7) << 4));
            a[rg] = *reinterpret_cast<const bf16x8*>(
                reinterpret_cast<const char*>(X) + byteoff);
        }
#pragma unroll
        for (int rg = 0; rg < 4; ++rg)
#pragma unroll
            for (int cg = 0; cg < 2; ++cg)
                acc2[rg][cg] = __builtin_amdgcn_mfma_f32_16x16x32_bf16(
                    a[rg], B2[cg][s], acc2[rg][cg], 0, 0, 0);
    }

    // residual write: h += update; refresh h_bf; h_new bf16 -> LDS @16KB
#pragma unroll
    for (int cg = 0; cg < 2; ++cg) {
        const int col = w * 32 + cg * 16 + l15;
        const float bb = b2[col];
#pragma unroll
        for (int rg = 0; rg < 4; ++rg) {
#pragma unroll
            for (int r = 0; r < 4; ++r) {
                const int row = rg * 16 + lq * 4 + r;
                const int n = n0 + row;
                if (n < N) {
                    const float hv = h[(size_t)n * H + col] + acc2[rg][cg][r] + bb;
                    h[(size_t)n * H + col] = hv;
                    const unsigned short hb = f2bf(hv);
                    h_bf[(size_t)n * H + col] = hb;
                    if (PROD) {
                        const int byteoff =
                            16384 + row * 256 + ((col * 2) ^ ((row & 7) << 4));
                        *reinterpret_cast<unsigned short*>(
                            reinterpret_cast<char*>(X) + byteoff) = hb;
                    }
                } else if (PROD) {
                    const int byteoff =
                        16384 + row * 256 + ((col * 2) ^ ((row & 7) << 4));
                    *reinterpret_cast<unsigned short*>(
                        reinterpret_cast<char*>(X) + byteoff) = 0;
                }
            }
        }
    }

    if (PROD) {
        bf16x8 B3[2][4], B4[2][4];
#pragma unroll
        for (int cg = 0; cg < 2; ++cg) {
            const int col = w * 32 + cg * 16 + l15;
#pragma unroll
            for (int s = 0; s < 4; ++s) {
                B3[cg][s] = *reinterpret_cast<const bf16x8*>(
                    eW1tN + (size_t)col * 256 + s * 32 + lq * 8);
                B4[cg][s] = *reinterpret_cast<const bf16x8*>(
                    eW1tN + (size_t)col * 256 + 128 + s * 32 + lq * 8);
            }
        }
        __syncthreads();

        f32x4 acc3[4][2], acc4[4][2];
#pragma unroll
        for (int rg = 0; rg < 4; ++rg)
#pragma unroll
            for (int cg = 0; cg < 2; ++cg) {
                acc3[rg][cg] = (f32x4)0.f;
                acc4[rg][cg] = (f32x4)0.f;
            }

#pragma unroll
        for (int s = 0; s < 4; ++s) {
            bf16x8 a[4];
#pragma unroll
            for (int rg = 0; rg < 4; ++rg) {
                const int row = rg * 16 + l15;
                const int byteoff =
                    16384 + row * 256 + ((s * 64 + lq * 16) ^ ((row & 7) << 4));
                a[rg] = *reinterpret_cast<const bf16x8*>(
                    reinterpret_cast<const char*>(X) + byteoff);
            }
#pragma unroll
            for (int rg = 0; rg < 4; ++rg)
#pragma unroll
                for (int cg = 0; cg < 2; ++cg) {
                    acc3[rg][cg] = __builtin_amdgcn_mfma_f32_16x16x32_bf16(
                        a[rg], B3[cg][s], acc3[rg][cg], 0, 0, 0);
                    acc4[rg][cg] = __builtin_amdgcn_mfma_f32_16x16x32_bf16(
                        a[rg], B4[cg][s], acc4[rg][cg], 0, 0, 0);
                }
        }

#pragma unroll
        for (int cg = 0; cg < 2; ++cg) {
            const int col = w * 32 + cg * 16 + l15;
            const float bb = eb1N[col];
#pragma unroll
            for (int rg = 0; rg < 4; ++rg) {
#pragma unroll
                for (int r = 0; r < 4; ++r) {
                    const int row = rg * 16 + lq * 4 + r;
                    const int n = n0 + row;
                    if (n < N) {
                        A_out[(size_t)n * H + col] = f2bf(acc3[rg][cg][r]);
                        B_out[(size_t)n * H + col] = acc4[rg][cg][r] + bb;
                    }
                }
            }
        }
    }
}

// --------------- decoder: h -> GELU MLP -> out [N,8] ----------------------
__global__ __launch_bounds__(NTHR) void decode_kernel(
    const float* __restrict__ h, const float* __restrict__ W1,
    const float* __restrict__ b1, const float* __restrict__ W2,
    const float* __restrict__ b2, float* __restrict__ out, int N) {
    __shared__ float xin[TILE * H];
    __shared__ float hm[TILE * 132];
    const int t = threadIdx.x;
    const int n0 = blockIdx.x * TILE;
    const int c0 = t & 63;
    const int eg = t >> 6;
    {
        const int col = t & 127;
        for (int e = t >> 7; e < TILE; e += 2) {
            const int n = n0 + e;
            xin[e * H + col] = (n < N) ? h[(size_t)n * H + col] : 0.f;
        }
    }
    __syncthreads();

    float a0[8], a1[8];
#pragma unroll
    for (int e = 0; e < 8; ++e) { a0[e] = 0.f; a1[e] = 0.f; }
    mlp_layer<32>(W1, xin, H, c0, eg * 8, a0, a1);
    {
        const float bb0 = b1[c0], bb1 = b1[c0 + 64];
#pragma unroll
        for (int e = 0; e < 8; ++e) {
            hm[(eg * 8 + e) * 132 + c0] = gelu_fast(a0[e] + bb0);
            hm[(eg * 8 + e) * 132 + c0 + 64] = gelu_fast(a1[e] + bb1);
        }
    }
    __syncthreads();
    {
        const int e = t >> 3;
        const int o = t & 7;
        const int n = n0 + e;
        float acc = b2[o];
#pragma unroll 4
        for (int k = 0; k < H; ++k)
            acc = fmaf(hm[e * 132 + k], W2[k * 8 + o], acc);
        if (n < N) out[n * 8 + o] = acc;
    }
}

extern "C" void kernel_launch(void* const* d_in, const int* in_sizes, int n_in,
                              void* d_out, int out_size, void* d_ws,
                              size_t ws_size, hipStream_t stream) {
    (void)n_in; (void)out_size; (void)ws_size;
    const float* nf      = (const float*)d_in[0];
    const int*   ei      = (const int*)d_in[1];
    const float* enc_W1  = (const float*)d_in[2];
    const float* enc_b1  = (const float*)d_in[3];
    const float* enc_W2  = (const float*)d_in[4];
    const float* enc_b2  = (const float*)d_in[5];
    const float* edge_W1 = (const float*)d_in[6];
    const float* edge_b1 = (const float*)d_in[7];
    const float* edge_W2 = (const float*)d_in[8];
    const float* edge_b2 = (const float*)d_in[9];
    const float* node_W1 = (const float*)d_in[10];
    const float* node_b1 = (const float*)d_in[11];
    const float* node_W2 = (const float*)d_in[12];
    const float* node_b2 = (const float*)d_in[13];
    const float* dec_W1  = (const float*)d_in[14];
    const float* dec_b1  = (const float*)d_in[15];
    const float* dec_W2  = (const float*)d_in[16];
    const float* dec_b2  = (const float*)d_in[17];

    const int N = in_sizes[0] / 16;
    const int E = in_sizes[1] / 2;
    const int L = in_sizes[7] / H;  // edge_b1 is [L,H]
    const int numChunks = E / CHUNK + 1;

    // ---------------- workspace layout ----------------
    char* ws = (char*)d_ws;
    float* h    = (float*)ws;                    ws += (size_t)N * H * 4;
    float* Bf32 = (float*)ws;                    ws += (size_t)N * H * 4;
    unsigned short* h_bf = (unsigned short*)ws;  ws += (size_t)N * H * 2;
    unsigned short* A_bf = (unsigned short*)ws;  ws += (size_t)N * H * 2;
    unsigned short* aggB = (unsigned short*)ws;  ws += (size_t)N * H * 2;
    int* srcS     = (int*)ws;                    ws += (size_t)E * 4;
    int* deg      = (int*)ws;                    ws += (size_t)N * 4;
    int* rowStart = (int*)ws;                    ws += (size_t)(N + 1) * 4;
    int* cursor   = (int*)ws;                    ws += (size_t)N * 4;
    int* bsum     = (int*)ws;                    ws += (size_t)256 * 4;
    int* chunkLo  = (int*)ws;                    ws += (size_t)numChunks * 4;
    unsigned short* eW1t = (unsigned short*)ws;  ws += (size_t)L * 2 * H * H * 2;
    unsigned short* nW1tc = (unsigned short*)ws; ws += (size_t)L * 2 * H * H * 2;
    unsigned short* nW2t = (unsigned short*)ws;  ws += (size_t)L * H * H * 2;
    float* cvec   = (float*)ws;                  ws += (size_t)L * H * 4;

    const int* srcArr = ei;
    const int* dstArr = ei + E;

    // ---- merged weight prep + wcomb + deg zeroing (one dispatch) ----
    {
        const int t1 = L * 2 * H * H, t2 = L * H * H;
        const int total = t1 + 2 * t2 + L * (H + 1) * H;
        prep_kernel<<<(total + NTHR - 1) / NTHR, NTHR, 0, stream>>>(
            edge_W1, node_W2, node_W1, edge_W2, edge_b2, eW1t, nW2t, nW1tc,
            cvec, deg, t1, t2, N);
    }

    // ---- sort edges by dst (hist + multiblock scan + merged finalize) ----
    deg_kernel<<<(E + NTHR - 1) / NTHR, NTHR, 0, stream>>>(dstArr, deg, E);
    const int nScanB = (N + 1023) / 1024;
    scan1_kernel<<<nScanB, 1024, 0, stream>>>(deg, rowStart, bsum, N);
    scan2_kernel<<<1, 64, 0, stream>>>(bsum, nScanB);
    const int scan3Span = (N + 1 > numChunks) ? (N + 1) : numChunks;
    scan3_kernel<<<(scan3Span + NTHR - 1) / NTHR, NTHR, 0, stream>>>(
        rowStart, cursor, bsum, chunkLo, N, E, numChunks);
    const int finSpan = (N > E) ? N : E;
    finalize_kernel<<<(finSpan + NTHR - 1) / NTHR, NTHR, 0, stream>>>(
        rowStart, chunkLo, srcArr, dstArr, cursor, srcS, N, E);

    const int encBlocks  = (N + TILE - 1) / TILE;
    const int nodeBlocks = (N + TE - 1) / TE;
    const int gatherBlks = (numChunks + 3) / 4;

    // fused encode + layer-0 A/B production
    encab_kernel<<<encBlocks, NTHR, 0, stream>>>(
        nf, enc_W1, enc_b1, enc_W2, enc_b2, h, h_bf, eW1t, edge_b1, A_bf,
        Bf32, N);
    for (int l = 0; l < L; ++l) {
        edge_gather_kernel<<<gatherBlks, NTHR, 0, stream>>>(
            A_bf, Bf32, srcS, rowStart, chunkLo, aggB, N, E);
        if (l + 1 < L) {
            node_fused_kernel<true><<<nodeBlocks, NTHR, 0, stream>>>(
                h, h_bf, aggB, deg, nW1tc + (size_t)l * 2 * H * H,
                node_b1 + (size_t)l * H, cvec + (size_t)l * H,
                nW2t + (size_t)l * H * H, node_b2 + (size_t)l * H,
                eW1t + (size_t)(l + 1) * 2 * H * H,
                edge_b1 + (size_t)(l + 1) * H, A_bf, Bf32, N);
        } else {
            node_fused_kernel<false><<<nodeBlocks, NTHR, 0, stream>>>(
                h, h_bf, aggB, deg, nW1tc + (size_t)l * 2 * H * H,
                node_b1 + (size_t)l * H, cvec + (size_t)l * H,
                nW2t + (size_t)l * H * H, node_b2 + (size_t)l * H, nullptr,
                nullptr, nullptr, nullptr, N);
        }
    }
    decode_kernel<<<encBlocks, NTHR, 0, stream>>>(h, dec_W1, dec_b1, dec_W2,
                                                  dec_b2, (float*)d_out, N);
}